// Round 6
// baseline (2365.782 us; speedup 1.0000x reference)
//
#include <hip/hip_runtime.h>
#include <hip/hip_bf16.h>
#include <math.h>

#define NN 50000
#define NFEAT 256
#define NHID 128
#define OUTD 64
#define NE 800000
#define NP 3
#define NCH 64
#define RC 782   // ceil(NN/NCH)
#define NSB 196  // ceil(NN/256) scan blocks
#define NNR (NN + 1)  // rowptr stride per plane
#define NBUK 256
#define BROWS 196   // ceil(NN/NBUK)
#define BCAP 4096   // mean bucket = 3136, +17 sigma

typedef __hip_bfloat16 bf16;
typedef __attribute__((ext_vector_type(8))) short short8;
typedef __attribute__((ext_vector_type(4))) short short4v;
typedef __attribute__((ext_vector_type(4))) float f32x4;
typedef unsigned long long u64;

static inline int cdiv(long a, long b) { return (int)((a + b - 1) / b); }

// RNE f32 -> bf16 bits (finite inputs only)
__device__ __forceinline__ short f2bf(float x) {
    unsigned u = __builtin_bit_cast(unsigned, x);
    unsigned r = (u + 0x7FFFu + ((u >> 16) & 1u)) >> 16;
    return (short)r;
}
__device__ __forceinline__ float bf2f(short b) {
    unsigned u = ((unsigned)(unsigned short)b) << 16;
    return __builtin_bit_cast(float, u);
}

__device__ __forceinline__ float telu_f(float x) {
    float e = __expf(x);
    float t = __expf(-2.0f * e);
    return x * (1.0f - t) / (1.0f + t);
}

__device__ __forceinline__ void ld8(const float* __restrict__ p, float v[8]) {
    float4 a = *reinterpret_cast<const float4*>(p);
    float4 b = *reinterpret_cast<const float4*>(p + 4);
    v[0] = a.x; v[1] = a.y; v[2] = a.z; v[3] = a.w;
    v[4] = b.x; v[5] = b.y; v[6] = b.z; v[7] = b.w;
}

__device__ __forceinline__ void store4(float* p, const float o[4]) {
    *reinterpret_cast<float4*>(p) = make_float4(o[0], o[1], o[2], o[3]);
}
__device__ __forceinline__ void store4(bf16* p, const float o[4]) {
    short4v u;
    u[0] = f2bf(o[0]); u[1] = f2bf(o[1]); u[2] = f2bf(o[2]); u[3] = f2bf(o[3]);
    *reinterpret_cast<short4v*>(p) = u;
}

// =============== weight prep: transpose + hi/lo bf16 split ===============
// src: (P,K,M) f32 row-major -> dh/dl: (P,M,K) bf16
__global__ void transpose_split(const float* __restrict__ src, bf16* __restrict__ dh,
                                bf16* __restrict__ dl, int K, int M, long total) {
    long idx = (long)blockIdx.x * blockDim.x + threadIdx.x;
    if (idx >= total) return;
    long pm = idx / K;
    int k = (int)(idx - pm * K);
    long p = pm / M;
    int m = (int)(pm - p * M);
    float v = src[(p * K + k) * M + m];
    short hb = f2bf(v);
    short lb = f2bf(v - bf2f(hb));
    reinterpret_cast<short*>(dh)[idx] = hb;
    reinterpret_cast<short*>(dl)[idx] = lb;
}

// =============== MFMA GEMM ===============
// out[n, m] = sum_k A[n,k] * B[k,m]  (B pre-transposed/split: Bh/Bl are [m][k] bf16)
// BM=64 rows/block, 4 waves x 16 rows, BK=32. hi/lo split on BOTH operands
// (3 MFMAs: ah*bh + ah*bl + al*bh) => f32-equivalent accuracy.
// MODE: 0 plain A[n*K+k]; 1 concat3 planes (spec_stack, K=192); 2 final mix (K=256)
// ACT: 0 none, 2 relu. OT: float or bf16.
template <int K, int M, int MODE, int ACT, typename OT>
__global__ __launch_bounds__(256) void gemm_mfma(
    const float* __restrict__ A, const bf16* __restrict__ Bh, const bf16* __restrict__ Bl,
    const float* __restrict__ bias, OT* __restrict__ out, int nrows,
    const float* __restrict__ wvec, const float* __restrict__ s1,
    const float* __restrict__ s2, const float* __restrict__ s3) {
    constexpr int MC = M / 16;
    __shared__ short AsH[64 * 32];
    __shared__ short AsL[64 * 32];

    int t = threadIdx.x;
    int n0 = blockIdx.x * 64;
    int w = t >> 6;
    int l = t & 63;
    int lr = l & 15, lq = l >> 4;

    float w0 = 0.f, w1 = 0.f, w2 = 0.f;
    if (MODE == 2) { w0 = wvec[3]; w1 = wvec[4]; w2 = wvec[5]; }

    f32x4 acc[MC];
#pragma unroll
    for (int i = 0; i < MC; ++i) {
        f32x4 z = {0.f, 0.f, 0.f, 0.f};
        acc[i] = z;
    }

    // staging coords: 256 threads cover 64 rows x 32 k; row = t>>2, 8-elem chunk = t&3
    int sr = t >> 2, sc = t & 3;
    int gn_s = n0 + sr;
    int wslot = (sc ^ ((sr >> 2) & 3)) << 3;   // XOR-swizzled 16B slot
    short* wpH = &AsH[sr * 32 + wslot];
    short* wpL = &AsL[sr * 32 + wslot];

    // fragment-read coords: wave w owns rows [w*16, w*16+16)
    int rrow = (w << 4) + lr;
    int roff = rrow * 32 + ((lq ^ ((rrow >> 2) & 3)) << 3);
    const short* rpH = &AsH[roff];
    const short* rpL = &AsL[roff];

    const short* Bhs = reinterpret_cast<const short*>(Bh);
    const short* Bls = reinterpret_cast<const short*>(Bl);

    auto loadA = [&](int k0, float v[8]) {
        if (gn_s >= nrows) {
#pragma unroll
            for (int j = 0; j < 8; ++j) v[j] = 0.f;
            return;
        }
        if (MODE == 0) {
            ld8(A + (long)gn_s * K + k0 + sc * 8, v);
        } else if (MODE == 1) {
            int plane = k0 >> 6;
            int d = (k0 & 63) + sc * 8;
            ld8(A + ((long)plane * NN + gn_s) * OUTD + d, v);
        } else {
            int seg = k0 >> 6;
            int d = (k0 & 63) + sc * 8;
            if (seg == 0) {
                float x0[8], x1[8], x2[8];
                ld8(A + ((long)0 * NN + gn_s) * OUTD + d, x0);
                ld8(A + ((long)1 * NN + gn_s) * OUTD + d, x1);
                ld8(A + ((long)2 * NN + gn_s) * OUTD + d, x2);
#pragma unroll
                for (int j = 0; j < 8; ++j) v[j] = w0 * x0[j] + w1 * x1[j] + w2 * x2[j];
            } else if (seg == 1) {
                float x0[8], x1[8], x2[8];
                ld8(s1 + ((long)0 * NN + gn_s) * OUTD + d, x0);
                ld8(s1 + ((long)1 * NN + gn_s) * OUTD + d, x1);
                ld8(s1 + ((long)2 * NN + gn_s) * OUTD + d, x2);
#pragma unroll
                for (int j = 0; j < 8; ++j) v[j] = (x0[j] + x1[j] + x2[j]) * (1.0f / 3.0f);
            } else if (seg == 2) {
                ld8(s2 + (long)gn_s * OUTD + d, v);
            } else {
                ld8(s3 + (long)gn_s * OUTD + d, v);
            }
        }
    };

    float v[8];
    loadA(0, v);
    for (int k0 = 0; k0 < K; k0 += 32) {
        short8 ah, al;
#pragma unroll
        for (int j = 0; j < 8; ++j) {
            short hb = f2bf(v[j]);
            ah[j] = hb;
            al[j] = f2bf(v[j] - bf2f(hb));
        }
        __syncthreads();  // previous iter's fragment reads done
        *reinterpret_cast<short8*>(wpH) = ah;
        *reinterpret_cast<short8*>(wpL) = al;
        __syncthreads();
        if (k0 + 32 < K) loadA(k0 + 32, v);  // prefetch next tile while MFMAs run
        short8 fah = *reinterpret_cast<const short8*>(rpH);
        short8 fal = *reinterpret_cast<const short8*>(rpL);
#pragma unroll
        for (int m = 0; m < MC; ++m) {
            long wb = (long)(m * 16 + lr) * K + k0 + (lq << 3);
            short8 bh = *reinterpret_cast<const short8*>(Bhs + wb);
            short8 bl = *reinterpret_cast<const short8*>(Bls + wb);
            // D layout (verified): m = (lane>>4)*4+reg, n = lane&15
            acc[m] = __builtin_amdgcn_mfma_f32_16x16x32_bf16(bh, fah, acc[m], 0, 0, 0);
            acc[m] = __builtin_amdgcn_mfma_f32_16x16x32_bf16(bl, fah, acc[m], 0, 0, 0);
            acc[m] = __builtin_amdgcn_mfma_f32_16x16x32_bf16(bh, fal, acc[m], 0, 0, 0);
        }
    }

    int gn = n0 + (w << 4) + lr;
    if (gn < nrows) {
#pragma unroll
        for (int m = 0; m < MC; ++m) {
            int mb = m * 16 + (lq << 2);
            float o[4];
#pragma unroll
            for (int r = 0; r < 4; ++r) {
                o[r] = acc[m][r] + (bias ? bias[mb + r] : 0.f);
                if (ACT == 2) o[r] = fmaxf(o[r], 0.f);
            }
            store4(&out[(long)gn * M + mb], o);
        }
    }
}

// =============== CSR build (hist + scan + bucketed two-pass scatter) ===============
__global__ void hist_all(const int* __restrict__ ei, int* __restrict__ cnt) {
    int p = blockIdx.y;
    int e = blockIdx.x * blockDim.x + threadIdx.x;
    if (e >= NE) return;
    int r = ei[((long)p * 2) * NE + e];
    atomicAdd(&cnt[(long)p * NN + r], 1);
}

// per-block sums of 256-chunks
__global__ void scan_pass1(const int* __restrict__ cnt, int* __restrict__ bsum) {
    int p = blockIdx.y, b = blockIdx.x, t = threadIdx.x;
    int idx = b * 256 + t;
    int v = (idx < NN) ? cnt[(long)p * NN + idx] : 0;
    __shared__ int sh[256];
    sh[t] = v;
    __syncthreads();
    for (int off = 128; off > 0; off >>= 1) {
        if (t < off) sh[t] += sh[t + off];
        __syncthreads();
    }
    if (t == 0) bsum[p * NSB + b] = sh[0];
}

// exclusive scan of the NSB block sums (one block per plane)
__global__ void scan_pass2(const int* __restrict__ bsum, int* __restrict__ boff) {
    int p = blockIdx.x, t = threadIdx.x;
    int v = (t < NSB) ? bsum[p * NSB + t] : 0;
    __shared__ int sh[256];
    sh[t] = v;
    __syncthreads();
    for (int off = 1; off < 256; off <<= 1) {
        int tmp = (t >= off) ? sh[t - off] : 0;
        __syncthreads();
        sh[t] += tmp;
        __syncthreads();
    }
    if (t < NSB) boff[p * NSB + t] = sh[t] - v;  // exclusive
}

// exclusive scan within block + block offset -> rowptr
__global__ void scan_pass3(const int* __restrict__ cnt, const int* __restrict__ boff,
                           int* __restrict__ rowptr) {
    int p = blockIdx.y, b = blockIdx.x, t = threadIdx.x;
    int idx = b * 256 + t;
    int v = (idx < NN) ? cnt[(long)p * NN + idx] : 0;
    __shared__ int sh[256];
    sh[t] = v;
    __syncthreads();
    for (int off = 1; off < 256; off <<= 1) {
        int tmp = (t >= off) ? sh[t - off] : 0;
        __syncthreads();
        sh[t] += tmp;
        __syncthreads();
    }
    int rp = boff[p * NSB + b] + sh[t] - v;
    if (idx < NN) rowptr[(long)p * NNR + idx] = rp;
    if (idx == NN - 1) rowptr[(long)p * NNR + NN] = rp + v;
}

// pass 1: append edge ids to row-range buckets (tail appends share cache lines)
__global__ void bucket_append(const int* __restrict__ ei, int* __restrict__ bcnt,
                              int* __restrict__ bbuf) {
    int p = blockIdx.y;
    int e = blockIdx.x * blockDim.x + threadIdx.x;
    if (e >= NE) return;
    int r = ei[((long)p * 2) * NE + e];
    int b = r / BROWS;
    int pos = atomicAdd(&bcnt[p * NBUK + b], 1);
    bbuf[((long)p * NBUK + b) * BCAP + pos] = e;
}

// pass 2: one workgroup per (bucket, plane); LDS row cursors; CSR writes confined
// to this bucket's ~75KB span, all from one CU -> lines assembled in one L2.
__global__ __launch_bounds__(256) void bucket_scatter(
    const int* __restrict__ ei, const float* __restrict__ ev,
    const int* __restrict__ bcnt, const int* __restrict__ bbuf,
    const int* __restrict__ rowptr, int2* __restrict__ csr) {
    int b = blockIdx.x, p = blockIdx.y;
    int t = threadIdx.x;
    int row0 = b * BROWS;
    int nrows = min(BROWS, NN - row0);
    __shared__ int cur[BROWS];
    for (int i = t; i < nrows; i += 256) cur[i] = rowptr[(long)p * NNR + row0 + i];
    __syncthreads();
    int cntb = bcnt[p * NBUK + b];
    const int* buf = bbuf + ((long)p * NBUK + b) * BCAP;
    const int* rs = ei + ((long)p * 2) * NE;
    const int* cs = rs + NE;
    const float* vs = ev + (long)p * NE;
    int2* csrp = csr + (long)p * NE;
    for (int i = t; i < cntb; i += 256) {
        int e = buf[i];
        int r = rs[e];
        int c = cs[e];
        float v = vs[e];
        int pos = atomicAdd(&cur[r - row0], 1);
        csrp[pos] = make_int2(c, __float_as_int(v));
    }
}

// =============== fused dual gather SpMM (bf16x2 gathers, packed csr) ===============
// RPB rows per block, M/2 threads per row. ACT: 0 none, 1 telu.
template <int M, int ACT, int RPB>
__global__ void spmm_dual(const int* __restrict__ rowptr, const int2* __restrict__ csr,
                          const bf16* __restrict__ Ya, const bf16* __restrict__ Yb,
                          const float* __restrict__ biasA, const float* __restrict__ biasB,
                          float* __restrict__ outA, float* __restrict__ outB) {
    constexpr int TPR = M / 2;
    int t = threadIdx.x;
    int n = blockIdx.x * RPB + t / TPR;
    int hs = t % TPR;          // bf16x2 slot
    int h = hs * 2;            // column
    if (n >= NN) return;
    int e0 = rowptr[n], e1 = rowptr[n + 1];
    float aAl = biasA[h], aAh = biasA[h + 1];
    float aBl = biasB[h], aBh = biasB[h + 1];
    const unsigned* Ua = reinterpret_cast<const unsigned*>(Ya);
    const unsigned* Ub = reinterpret_cast<const unsigned*>(Yb);
    int e = e0;
    for (; e + 3 < e1; e += 4) {
        int2 p0 = csr[e], p1 = csr[e + 1], p2 = csr[e + 2], p3 = csr[e + 3];
        unsigned a0 = Ua[(long)p0.x * TPR + hs], a1 = Ua[(long)p1.x * TPR + hs];
        unsigned a2 = Ua[(long)p2.x * TPR + hs], a3 = Ua[(long)p3.x * TPR + hs];
        unsigned b0 = Ub[(long)p0.x * TPR + hs], b1 = Ub[(long)p1.x * TPR + hs];
        unsigned b2 = Ub[(long)p2.x * TPR + hs], b3 = Ub[(long)p3.x * TPR + hs];
        float v0 = __int_as_float(p0.y), v1 = __int_as_float(p1.y);
        float v2 = __int_as_float(p2.y), v3 = __int_as_float(p3.y);
        aAl += v0 * bf2f((short)a0) + v1 * bf2f((short)a1) + v2 * bf2f((short)a2) + v3 * bf2f((short)a3);
        aAh += v0 * bf2f((short)(a0 >> 16)) + v1 * bf2f((short)(a1 >> 16)) +
               v2 * bf2f((short)(a2 >> 16)) + v3 * bf2f((short)(a3 >> 16));
        aBl += v0 * bf2f((short)b0) + v1 * bf2f((short)b1) + v2 * bf2f((short)b2) + v3 * bf2f((short)b3);
        aBh += v0 * bf2f((short)(b0 >> 16)) + v1 * bf2f((short)(b1 >> 16)) +
               v2 * bf2f((short)(b2 >> 16)) + v3 * bf2f((short)(b3 >> 16));
    }
    for (; e < e1; ++e) {
        int2 pe = csr[e];
        float v = __int_as_float(pe.y);
        unsigned a = Ua[(long)pe.x * TPR + hs];
        unsigned b = Ub[(long)pe.x * TPR + hs];
        aAl += v * bf2f((short)a);
        aAh += v * bf2f((short)(a >> 16));
        aBl += v * bf2f((short)b);
        aBh += v * bf2f((short)(b >> 16));
    }
    if (ACT == 1) {
        aAl = telu_f(aAl); aAh = telu_f(aAh);
        aBl = telu_f(aBl); aBh = telu_f(aBh);
    }
    *reinterpret_cast<float2*>(&outA[(long)n * M + h]) = make_float2(aAl, aAh);
    *reinterpret_cast<float2*>(&outB[(long)n * M + h]) = make_float2(aBl, aBh);
}

// merged 3-plane spmm (bf16x2 gathers); 2 rows per 64-thread block
__global__ void spmm_merged(const int* __restrict__ rp0, const int2* __restrict__ cs0,
                            const int* __restrict__ rp1, const int2* __restrict__ cs1,
                            const int* __restrict__ rp2, const int2* __restrict__ cs2,
                            const bf16* __restrict__ Y, const float* __restrict__ wvec,
                            const float* __restrict__ bias, float* __restrict__ out) {
    constexpr int TPR = 32;
    int t = threadIdx.x;
    int n = blockIdx.x * 2 + t / TPR;
    int hs = t % TPR;
    int h = hs * 2;
    if (n >= NN) return;
    const int* rps[3] = {rp0, rp1, rp2};
    const int2* css[3] = {cs0, cs1, cs2};
    const unsigned* U = reinterpret_cast<const unsigned*>(Y);
    float al = 0.f, ah = 0.f;
#pragma unroll
    for (int p = 0; p < 3; ++p) {
        const int2* cs = css[p];
        int e0 = rps[p][n], e1 = rps[p][n + 1];
        float sl = 0.f, sh = 0.f;
        int e = e0;
        for (; e + 3 < e1; e += 4) {
            int2 p0 = cs[e], p1 = cs[e + 1], p2 = cs[e + 2], p3 = cs[e + 3];
            unsigned y0 = U[(long)p0.x * TPR + hs], y1 = U[(long)p1.x * TPR + hs];
            unsigned y2 = U[(long)p2.x * TPR + hs], y3 = U[(long)p3.x * TPR + hs];
            float v0 = __int_as_float(p0.y), v1 = __int_as_float(p1.y);
            float v2 = __int_as_float(p2.y), v3 = __int_as_float(p3.y);
            sl += v0 * bf2f((short)y0) + v1 * bf2f((short)y1) + v2 * bf2f((short)y2) + v3 * bf2f((short)y3);
            sh += v0 * bf2f((short)(y0 >> 16)) + v1 * bf2f((short)(y1 >> 16)) +
                  v2 * bf2f((short)(y2 >> 16)) + v3 * bf2f((short)(y3 >> 16));
        }
        for (; e < e1; ++e) {
            int2 pe = cs[e];
            unsigned y = U[(long)pe.x * TPR + hs];
            float v = __int_as_float(pe.y);
            sl += v * bf2f((short)y);
            sh += v * bf2f((short)(y >> 16));
        }
        float wv = wvec[p];
        al += wv * sl;
        ah += wv * sh;
    }
    *reinterpret_cast<float2*>(&out[(long)n * OUTD + h]) =
        make_float2(al + bias[h], ah + bias[h + 1]);
}

// =============== column summaries (coalesced, chunked) ===============
__global__ void colsum_passA(const float* __restrict__ spec, float* __restrict__ pmax,
                             float* __restrict__ psum, float* __restrict__ pexp) {
    int p = blockIdx.y, c = blockIdx.x;
    int t = threadIdx.x;
    int d = t & 63, rg = t >> 6;
    const float* base = spec + (long)p * NN * OUTD;
    int r0 = c * RC, r1 = min(r0 + RC, NN);
    float m = -INFINITY, s = 0.f, e = 0.f;
    for (int r = r0 + rg; r < r1; r += 4) {
        float v = base[(long)r * OUTD + d];
        s += v;
        if (v > m) { e = e * __expf(m - v) + 1.0f; m = v; }
        else e += __expf(v - m);
    }
    __shared__ float rm[256], rs[256], re[256];
    rm[t] = m; rs[t] = s; re[t] = e;
    __syncthreads();
    for (int off = 128; off >= 64; off >>= 1) {
        if (t < off) {
            float m2 = fmaxf(rm[t], rm[t + off]);
            re[t] = re[t] * __expf(rm[t] - m2) + re[t + off] * __expf(rm[t + off] - m2);
            rm[t] = m2;
            rs[t] = rs[t] + rs[t + off];
        }
        __syncthreads();
    }
    if (t < 64) {
        long idx = ((long)p * 64 + t) * NCH + c;
        pmax[idx] = rm[t]; psum[idx] = rs[t]; pexp[idx] = re[t];
    }
}

__global__ void colsum_reduceB(const float* __restrict__ pmax, const float* __restrict__ psum,
                               const float* __restrict__ pexp, float* __restrict__ ps,
                               float* __restrict__ zbuf) {
    int b = blockIdx.x;
    int p = b >> 6, d = b & 63;
    int t = threadIdx.x;
    long idx = (long)b * NCH + t;
    float m = pmax[idx], s = psum[idx], e = pexp[idx];
    for (int off = 32; off > 0; off >>= 1) {
        float m2 = fmaxf(m, __shfl_xor(m, off));
        e = e * __expf(m - m2) + __shfl_xor(e, off) * __expf(__shfl_xor(m, off) - m2);
        m = m2;
        s += __shfl_xor(s, off);
    }
    if (t == 0) {
        ps[p * 192 + d] = s / (float)NN;
        ps[p * 192 + 64 + d] = m;
        zbuf[b] = e;
    }
}

__global__ void colsum_passC(const float* __restrict__ spec, const float* __restrict__ ps,
                             const float* __restrict__ zbuf, float* __restrict__ pent) {
    int p = blockIdx.y, c = blockIdx.x;
    int t = threadIdx.x;
    int d = t & 63, rg = t >> 6;
    const float* base = spec + (long)p * NN * OUTD;
    float gm = ps[p * 192 + 64 + d];
    float zinv = 1.0f / zbuf[p * 64 + d];
    int r0 = c * RC, r1 = min(r0 + RC, NN);
    float ent = 0.f;
    for (int r = r0 + rg; r < r1; r += 4) {
        float v = base[(long)r * OUTD + d];
        float pv = __expf(v - gm) * zinv;
        ent -= pv * __logf(pv + 1e-6f);
    }
    __shared__ float rd[256];
    rd[t] = ent;
    __syncthreads();
    for (int off = 128; off >= 64; off >>= 1) {
        if (t < off) rd[t] += rd[t + off];
        __syncthreads();
    }
    if (t < 64) pent[((long)p * 64 + t) * NCH + c] = rd[t];
}

__global__ void colsum_reduceD(const float* __restrict__ pent, float* __restrict__ ps) {
    int b = blockIdx.x;
    int p = b >> 6, d = b & 63;
    int t = threadIdx.x;
    float e = pent[(long)b * NCH + t];
    for (int off = 32; off > 0; off >>= 1) e += __shfl_xor(e, off);
    if (t == 0) ps[p * 192 + 128 + d] = e;
}

// =============== walk + epilogue ===============
__global__ void walk_kernel(const float* __restrict__ ps, const float* __restrict__ weight_b,
                            const float* __restrict__ tau_p, float* __restrict__ wout) {
    if (threadIdx.x != 0 || blockIdx.x != 0) return;
    float sim[3][3];
    float inv = 1.0f / (sqrtf(192.0f) * tau_p[0]);
    for (int i = 0; i < 3; ++i)
        for (int j = 0; j < 3; ++j) {
            float dotv = 0.f;
            for (int k = 0; k < 192; ++k) dotv += ps[i * 192 + k] * ps[j * 192 + k];
            sim[i][j] = dotv * inv;
        }
    float T[3][3];
    for (int i = 0; i < 3; ++i) {
        float m = fmaxf(sim[i][0], fmaxf(sim[i][1], sim[i][2]));
        float e0 = expf(sim[i][0] - m), e1 = expf(sim[i][1] - m), e2 = expf(sim[i][2] - m);
        float s = e0 + e1 + e2;
        T[i][0] = e0 / s; T[i][1] = e1 / s; T[i][2] = e2 / s;
    }
    float b0 = weight_b[0], b1 = weight_b[1], b2 = weight_b[2];
    float m = fmaxf(b0, fmaxf(b1, b2));
    float e0 = expf(b0 - m), e1 = expf(b1 - m), e2 = expf(b2 - m);
    float s = e0 + e1 + e2;
    float pi0[3] = {e0 / s, e1 / s, e2 / s};
    float pi[3] = {pi0[0], pi0[1], pi0[2]};
    for (int it = 0; it < 13; ++it) {
        float n0 = pi[0] * T[0][0] + pi[1] * T[1][0] + pi[2] * T[2][0];
        float n1 = pi[0] * T[0][1] + pi[1] * T[1][1] + pi[2] * T[2][1];
        float n2 = pi[0] * T[0][2] + pi[1] * T[1][2] + pi[2] * T[2][2];
        pi[0] = 0.2f * pi0[0] + 0.8f * n0;
        pi[1] = 0.2f * pi0[1] + 0.8f * n1;
        pi[2] = 0.2f * pi0[2] + 0.8f * n2;
    }
    wout[0] = pi[0]; wout[1] = pi[1]; wout[2] = pi[2];
    float mm = fmaxf(pi[0], fmaxf(pi[1], pi[2]));
    float f0 = expf(pi[0] - mm), f1 = expf(pi[1] - mm), f2 = expf(pi[2] - mm);
    float fs = f0 + f1 + f2;
    wout[3] = f0 / fs; wout[4] = f1 / fs; wout[5] = f2 / fs;
}

__global__ void hraw_final(const float* __restrict__ U1, float* __restrict__ Hraw) {
    long i = (long)blockIdx.x * blockDim.x + threadIdx.x;
    if (i >= (long)NN * OUTD) return;
    Hraw[i] = 0.5f * (U1[i] + Hraw[i]);
}

extern "C" void kernel_launch(void* const* d_in, const int* in_sizes, int n_in,
                              void* d_out, int out_size, void* d_ws, size_t ws_size,
                              hipStream_t stream) {
    const float* feature   = (const float*)d_in[0];
    const int*   edge_index= (const int*)d_in[1];
    const float* edge_val  = (const float*)d_in[2];
    const float* spec_w1   = (const float*)d_in[3];
    const float* spec_b1   = (const float*)d_in[4];
    const float* spec_w2   = (const float*)d_in[5];
    const float* spec_b2   = (const float*)d_in[6];
    const float* shared_w1 = (const float*)d_in[7];
    const float* shared_b1 = (const float*)d_in[8];
    const float* shared_w2 = (const float*)d_in[9];
    const float* shared_b2 = (const float*)d_in[10];
    const float* weight_b  = (const float*)d_in[11];
    const float* tau       = (const float*)d_in[12];
    const float* mlp_w1    = (const float*)d_in[13];
    const float* mlp_b1    = (const float*)d_in[14];
    const float* mlp_w2    = (const float*)d_in[15];
    const float* mlp_b2    = (const float*)d_in[16];
    const float* raw_w1    = (const float*)d_in[17];
    const float* raw_b1    = (const float*)d_in[18];
    const float* raw_w2    = (const float*)d_in[19];
    const float* raw_b2    = (const float*)d_in[20];
    const float* proj_w    = (const float*)d_in[21];
    const float* proj_b    = (const float*)d_in[22];

    float* out        = (float*)d_out;
    float* spec_stack = out + (long)NN * OUTD;
    float* shr_stack  = spec_stack + 3L * NN * OUTD;
    float* Hcol       = out + 7L * NN * OUTD;
    float* Hraw       = out + 8L * NN * OUTD;

    // ---- workspace carve ----
    char* wp = (char*)d_ws;
    bf16* XWsp = (bf16*)wp; wp += (long)NN * 128 * sizeof(bf16);
    bf16* XWsh = (bf16*)wp; wp += (long)NN * 128 * sizeof(bf16);
    bf16* Bsp  = (bf16*)wp; wp += (long)NN * OUTD * sizeof(bf16);
    bf16* Bsh  = (bf16*)wp; wp += (long)NN * OUTD * sizeof(bf16);
    float* h1sp = (float*)wp; wp += (long)NN * 128 * sizeof(float);
    float* h1sh = (float*)wp; wp += (long)NN * 128 * sizeof(float);
    float* psBuf = (float*)wp; wp += 1024 * sizeof(float);
    float* wBuf  = (float*)wp; wp += 64 * sizeof(float);
    float* zBuf  = (float*)wp; wp += 256 * sizeof(float);
    float* pMax  = (float*)wp; wp += (long)3 * 64 * NCH * sizeof(float);
    float* pSum  = (float*)wp; wp += (long)3 * 64 * NCH * sizeof(float);
    float* pExp  = (float*)wp; wp += (long)3 * 64 * NCH * sizeof(float);
    float* pEnt  = (float*)wp; wp += (long)3 * 64 * NCH * sizeof(float);
    int2* csr_all = (int2*)wp;  wp += (long)NP * NE * sizeof(int2);
    int*  rowptr_all = (int*)wp; wp += (long)NP * NNR * sizeof(int) + 64;
    int* cnt    = (int*)wp; wp += (long)NP * NN * sizeof(int);
    int* bsum   = (int*)wp; wp += (long)NP * NSB * sizeof(int);
    int* boff   = (int*)wp; wp += (long)NP * NSB * sizeof(int);
    int* bcnt   = (int*)wp; wp += (long)NP * NBUK * sizeof(int);
    int* bbuf   = (int*)wp; wp += (long)NP * NBUK * BCAP * sizeof(int);
    // pre-split transposed weights (bf16 hi/lo, [m][k] layout)
    bf16* w1sp_h = (bf16*)wp; wp += 3L * 256 * 128 * sizeof(bf16);
    bf16* w1sp_l = (bf16*)wp; wp += 3L * 256 * 128 * sizeof(bf16);
    bf16* w1sh_h = (bf16*)wp; wp += 256L * 128 * sizeof(bf16);
    bf16* w1sh_l = (bf16*)wp; wp += 256L * 128 * sizeof(bf16);
    bf16* w2sp_h = (bf16*)wp; wp += 3L * 128 * 64 * sizeof(bf16);
    bf16* w2sp_l = (bf16*)wp; wp += 3L * 128 * 64 * sizeof(bf16);
    bf16* w2sh_h = (bf16*)wp; wp += 128L * 64 * sizeof(bf16);
    bf16* w2sh_l = (bf16*)wp; wp += 128L * 64 * sizeof(bf16);
    bf16* mlp1_h = (bf16*)wp; wp += 192L * 128 * sizeof(bf16);
    bf16* mlp1_l = (bf16*)wp; wp += 192L * 128 * sizeof(bf16);
    bf16* mlp2_h = (bf16*)wp; wp += 128L * 64 * sizeof(bf16);
    bf16* mlp2_l = (bf16*)wp; wp += 128L * 64 * sizeof(bf16);
    bf16* raw1_h = (bf16*)wp; wp += 256L * 64 * sizeof(bf16);
    bf16* raw1_l = (bf16*)wp; wp += 256L * 64 * sizeof(bf16);
    bf16* raw2_h = (bf16*)wp; wp += 64L * 64 * sizeof(bf16);
    bf16* raw2_l = (bf16*)wp; wp += 64L * 64 * sizeof(bf16);
    bf16* proj_h = (bf16*)wp; wp += 256L * 64 * sizeof(bf16);
    bf16* proj_l = (bf16*)wp; wp += 256L * 64 * sizeof(bf16);

    int* rowptr[NP]; int2* csr[NP];
    for (int p = 0; p < NP; ++p) {
        rowptr[p] = rowptr_all + (long)p * NNR;
        csr[p]    = csr_all + (long)p * NE;
    }

    const int TB = 256;
    int g_rows = cdiv(NN, 64);  // 782

    // ---- weight prep (transpose + hi/lo split) ----
    transpose_split<<<cdiv(3L * 256 * 128, TB), TB, 0, stream>>>(spec_w1, w1sp_h, w1sp_l, 256, 128, 3L * 256 * 128);
    transpose_split<<<cdiv(256L * 128, TB), TB, 0, stream>>>(shared_w1, w1sh_h, w1sh_l, 256, 128, 256L * 128);
    transpose_split<<<cdiv(3L * 128 * 64, TB), TB, 0, stream>>>(spec_w2, w2sp_h, w2sp_l, 128, 64, 3L * 128 * 64);
    transpose_split<<<cdiv(128L * 64, TB), TB, 0, stream>>>(shared_w2, w2sh_h, w2sh_l, 128, 64, 128L * 64);
    transpose_split<<<cdiv(192L * 128, TB), TB, 0, stream>>>(mlp_w1, mlp1_h, mlp1_l, 192, 128, 192L * 128);
    transpose_split<<<cdiv(128L * 64, TB), TB, 0, stream>>>(mlp_w2, mlp2_h, mlp2_l, 128, 64, 128L * 64);
    transpose_split<<<cdiv(256L * 64, TB), TB, 0, stream>>>(raw_w1, raw1_h, raw1_l, 256, 64, 256L * 64);
    transpose_split<<<cdiv(64L * 64, TB), TB, 0, stream>>>(raw_w2, raw2_h, raw2_l, 64, 64, 64L * 64);
    transpose_split<<<cdiv(256L * 64, TB), TB, 0, stream>>>(proj_w, proj_h, proj_l, 256, 64, 256L * 64);

    // ---- build CSR (hist+scan, bucketed two-pass scatter) ----
    hipMemsetAsync(cnt, 0, (long)NP * NN * sizeof(int), stream);
    hipMemsetAsync(bcnt, 0, (long)NP * NBUK * sizeof(int), stream);
    {
        dim3 gE(cdiv(NE, TB), NP);
        hist_all<<<gE, TB, 0, stream>>>(edge_index, cnt);
        bucket_append<<<gE, TB, 0, stream>>>(edge_index, bcnt, bbuf);
        dim3 gS(NSB, NP);
        scan_pass1<<<gS, 256, 0, stream>>>(cnt, bsum);
        scan_pass2<<<NP, 256, 0, stream>>>(bsum, boff);
        scan_pass3<<<gS, 256, 0, stream>>>(cnt, boff, rowptr_all);
        dim3 gB(NBUK, NP);
        bucket_scatter<<<gB, 256, 0, stream>>>(edge_index, edge_val, bcnt, bbuf,
                                               rowptr_all, csr_all);
    }

    // ---- shared layer-1 GEMM (once) ----
    gemm_mfma<256, 128, 0, 0, bf16><<<g_rows, 256, 0, stream>>>(
        feature, w1sh_h, w1sh_l, nullptr, XWsh, NN, nullptr, nullptr, nullptr, nullptr);

    // ---- per plane: fused spec+shared pipeline ----
    for (int p = 0; p < NP; ++p) {
        gemm_mfma<256, 128, 0, 0, bf16><<<g_rows, 256, 0, stream>>>(
            feature, w1sp_h + (long)p * 256 * 128, w1sp_l + (long)p * 256 * 128,
            nullptr, XWsp, NN, nullptr, nullptr, nullptr, nullptr);
        spmm_dual<128, 1, 1><<<NN, 64, 0, stream>>>(rowptr[p], csr[p], XWsp, XWsh,
                                                    spec_b1 + (long)p * 128, shared_b1,
                                                    h1sp, h1sh);
        gemm_mfma<128, 64, 0, 0, bf16><<<g_rows, 256, 0, stream>>>(
            h1sp, w2sp_h + (long)p * 128 * 64, w2sp_l + (long)p * 128 * 64,
            nullptr, Bsp, NN, nullptr, nullptr, nullptr, nullptr);
        gemm_mfma<128, 64, 0, 0, bf16><<<g_rows, 256, 0, stream>>>(
            h1sh, w2sh_h, w2sh_l, nullptr, Bsh, NN, nullptr, nullptr, nullptr, nullptr);
        spmm_dual<64, 0, 2><<<cdiv(NN, 2), 64, 0, stream>>>(rowptr[p], csr[p], Bsp, Bsh,
                                                            spec_b2 + (long)p * 64, shared_b2,
                                                            spec_stack + (long)p * NN * OUTD,
                                                            shr_stack + (long)p * NN * OUTD);
    }

    // ---- summaries + random walk ----
    {
        dim3 gA(NCH, 3);
        colsum_passA<<<gA, 256, 0, stream>>>(spec_stack, pMax, pSum, pExp);
        colsum_reduceB<<<192, 64, 0, stream>>>(pMax, pSum, pExp, psBuf, zBuf);
        colsum_passC<<<gA, 256, 0, stream>>>(spec_stack, psBuf, zBuf, pEnt);
        colsum_reduceD<<<192, 64, 0, stream>>>(pEnt, psBuf);
    }
    walk_kernel<<<1, 64, 0, stream>>>(psBuf, weight_b, tau, wBuf);

    // ---- H_col (hidden reuses h1sp) ----
    gemm_mfma<192, 128, 1, 2, float><<<g_rows, 256, 0, stream>>>(
        spec_stack, mlp1_h, mlp1_l, mlp_b1, h1sp, NN, nullptr, nullptr, nullptr, nullptr);
    gemm_mfma<128, 64, 0, 0, float><<<g_rows, 256, 0, stream>>>(
        h1sp, mlp2_h, mlp2_l, mlp_b2, Hcol, NN, nullptr, nullptr, nullptr, nullptr);

    // ---- H_raw (U1 reuses h1sh; RB1/RB2 reuse Bsp/Bsh) ----
    float* U1 = h1sh;
    gemm_mfma<256, 64, 0, 0, bf16><<<g_rows, 256, 0, stream>>>(
        feature, raw1_h, raw1_l, nullptr, Bsp, NN, nullptr, nullptr, nullptr, nullptr);
    spmm_merged<<<cdiv(NN, 2), 64, 0, stream>>>(rowptr[0], csr[0],
                                                rowptr[1], csr[1],
                                                rowptr[2], csr[2],
                                                Bsp, wBuf, raw_b1, U1);
    gemm_mfma<64, 64, 0, 0, bf16><<<g_rows, 256, 0, stream>>>(
        U1, raw2_h, raw2_l, nullptr, Bsh, NN, nullptr, nullptr, nullptr, nullptr);
    spmm_merged<<<cdiv(NN, 2), 64, 0, stream>>>(rowptr[0], csr[0],
                                                rowptr[1], csr[1],
                                                rowptr[2], csr[2],
                                                Bsh, wBuf, raw_b2, Hraw);
    hraw_final<<<cdiv((long)NN * OUTD, TB), TB, 0, stream>>>(U1, Hraw);

    // ---- final projection (mix fused into A-loader) ----
    gemm_mfma<256, 64, 2, 0, float><<<g_rows, 256, 0, stream>>>(
        spec_stack, proj_h, proj_l, proj_b, out, NN, wBuf, shr_stack, Hcol, Hraw);
}

// Round 7
// 1513.031 us; speedup vs baseline: 1.5636x; 1.5636x over previous
//
#include <hip/hip_runtime.h>
#include <hip/hip_bf16.h>
#include <math.h>

#define NN 50000
#define NFEAT 256
#define NHID 128
#define OUTD 64
#define NE 800000
#define NP 3
#define NCH 64
#define RC 782   // ceil(NN/NCH)
#define NSB 196  // ceil(NN/256) scan blocks
#define NNR (NN + 1)  // rowptr stride per plane
#define NBUK 256
#define BROWS 196   // ceil(NN/NBUK)
#define BCAP 4096   // mean bucket = 3136, +17 sigma
#define EPB 8192    // edges per append block

typedef __hip_bfloat16 bf16;
typedef __attribute__((ext_vector_type(8))) short short8;
typedef __attribute__((ext_vector_type(4))) short short4v;
typedef __attribute__((ext_vector_type(4))) float f32x4;
typedef unsigned long long u64;

static inline int cdiv(long a, long b) { return (int)((a + b - 1) / b); }

// RNE f32 -> bf16 bits (finite inputs only)
__device__ __forceinline__ short f2bf(float x) {
    unsigned u = __builtin_bit_cast(unsigned, x);
    unsigned r = (u + 0x7FFFu + ((u >> 16) & 1u)) >> 16;
    return (short)r;
}
__device__ __forceinline__ float bf2f(short b) {
    unsigned u = ((unsigned)(unsigned short)b) << 16;
    return __builtin_bit_cast(float, u);
}

__device__ __forceinline__ float telu_f(float x) {
    float e = __expf(x);
    float t = __expf(-2.0f * e);
    return x * (1.0f - t) / (1.0f + t);
}

__device__ __forceinline__ void ld8(const float* __restrict__ p, float v[8]) {
    float4 a = *reinterpret_cast<const float4*>(p);
    float4 b = *reinterpret_cast<const float4*>(p + 4);
    v[0] = a.x; v[1] = a.y; v[2] = a.z; v[3] = a.w;
    v[4] = b.x; v[5] = b.y; v[6] = b.z; v[7] = b.w;
}

__device__ __forceinline__ void store4(float* p, const float o[4]) {
    *reinterpret_cast<float4*>(p) = make_float4(o[0], o[1], o[2], o[3]);
}
__device__ __forceinline__ void store4(bf16* p, const float o[4]) {
    short4v u;
    u[0] = f2bf(o[0]); u[1] = f2bf(o[1]); u[2] = f2bf(o[2]); u[3] = f2bf(o[3]);
    *reinterpret_cast<short4v*>(p) = u;
}

// =============== weight prep: transpose + hi/lo bf16 split ===============
// src: (P,K,M) f32 row-major -> dh/dl: (P,M,K) bf16
__global__ void transpose_split(const float* __restrict__ src, bf16* __restrict__ dh,
                                bf16* __restrict__ dl, int K, int M, long total) {
    long idx = (long)blockIdx.x * blockDim.x + threadIdx.x;
    if (idx >= total) return;
    long pm = idx / K;
    int k = (int)(idx - pm * K);
    long p = pm / M;
    int m = (int)(pm - p * M);
    float v = src[(p * K + k) * M + m];
    short hb = f2bf(v);
    short lb = f2bf(v - bf2f(hb));
    reinterpret_cast<short*>(dh)[idx] = hb;
    reinterpret_cast<short*>(dl)[idx] = lb;
}

// =============== MFMA GEMM ===============
// out[n, m] = sum_k A[n,k] * B[k,m]  (B pre-transposed/split: Bh/Bl are [m][k] bf16)
// BM=64 rows/block, 4 waves x 16 rows, BK=32. hi/lo split on BOTH operands
// (3 MFMAs: ah*bh + ah*bl + al*bh) => f32-equivalent accuracy.
// MODE: 0 plain A[n*K+k]; 1 concat3 planes (spec_stack, K=192); 2 final mix (K=256)
// ACT: 0 none, 2 relu. OT: float or bf16.
template <int K, int M, int MODE, int ACT, typename OT>
__global__ __launch_bounds__(256) void gemm_mfma(
    const float* __restrict__ A, const bf16* __restrict__ Bh, const bf16* __restrict__ Bl,
    const float* __restrict__ bias, OT* __restrict__ out, int nrows,
    const float* __restrict__ wvec, const float* __restrict__ s1,
    const float* __restrict__ s2, const float* __restrict__ s3) {
    constexpr int MC = M / 16;
    __shared__ short AsH[64 * 32];
    __shared__ short AsL[64 * 32];

    int t = threadIdx.x;
    int n0 = blockIdx.x * 64;
    int w = t >> 6;
    int l = t & 63;
    int lr = l & 15, lq = l >> 4;

    float w0 = 0.f, w1 = 0.f, w2 = 0.f;
    if (MODE == 2) { w0 = wvec[3]; w1 = wvec[4]; w2 = wvec[5]; }

    f32x4 acc[MC];
#pragma unroll
    for (int i = 0; i < MC; ++i) {
        f32x4 z = {0.f, 0.f, 0.f, 0.f};
        acc[i] = z;
    }

    // staging coords: 256 threads cover 64 rows x 32 k; row = t>>2, 8-elem chunk = t&3
    int sr = t >> 2, sc = t & 3;
    int gn_s = n0 + sr;
    int wslot = (sc ^ ((sr >> 2) & 3)) << 3;   // XOR-swizzled 16B slot
    short* wpH = &AsH[sr * 32 + wslot];
    short* wpL = &AsL[sr * 32 + wslot];

    // fragment-read coords: wave w owns rows [w*16, w*16+16)
    int rrow = (w << 4) + lr;
    int roff = rrow * 32 + ((lq ^ ((rrow >> 2) & 3)) << 3);
    const short* rpH = &AsH[roff];
    const short* rpL = &AsL[roff];

    const short* Bhs = reinterpret_cast<const short*>(Bh);
    const short* Bls = reinterpret_cast<const short*>(Bl);

    auto loadA = [&](int k0, float v[8]) {
        if (gn_s >= nrows) {
#pragma unroll
            for (int j = 0; j < 8; ++j) v[j] = 0.f;
            return;
        }
        if (MODE == 0) {
            ld8(A + (long)gn_s * K + k0 + sc * 8, v);
        } else if (MODE == 1) {
            int plane = k0 >> 6;
            int d = (k0 & 63) + sc * 8;
            ld8(A + ((long)plane * NN + gn_s) * OUTD + d, v);
        } else {
            int seg = k0 >> 6;
            int d = (k0 & 63) + sc * 8;
            if (seg == 0) {
                float x0[8], x1[8], x2[8];
                ld8(A + ((long)0 * NN + gn_s) * OUTD + d, x0);
                ld8(A + ((long)1 * NN + gn_s) * OUTD + d, x1);
                ld8(A + ((long)2 * NN + gn_s) * OUTD + d, x2);
#pragma unroll
                for (int j = 0; j < 8; ++j) v[j] = w0 * x0[j] + w1 * x1[j] + w2 * x2[j];
            } else if (seg == 1) {
                float x0[8], x1[8], x2[8];
                ld8(s1 + ((long)0 * NN + gn_s) * OUTD + d, x0);
                ld8(s1 + ((long)1 * NN + gn_s) * OUTD + d, x1);
                ld8(s1 + ((long)2 * NN + gn_s) * OUTD + d, x2);
#pragma unroll
                for (int j = 0; j < 8; ++j) v[j] = (x0[j] + x1[j] + x2[j]) * (1.0f / 3.0f);
            } else if (seg == 2) {
                ld8(s2 + (long)gn_s * OUTD + d, v);
            } else {
                ld8(s3 + (long)gn_s * OUTD + d, v);
            }
        }
    };

    float v[8];
    loadA(0, v);
    for (int k0 = 0; k0 < K; k0 += 32) {
        short8 ah, al;
#pragma unroll
        for (int j = 0; j < 8; ++j) {
            short hb = f2bf(v[j]);
            ah[j] = hb;
            al[j] = f2bf(v[j] - bf2f(hb));
        }
        __syncthreads();  // previous iter's fragment reads done
        *reinterpret_cast<short8*>(wpH) = ah;
        *reinterpret_cast<short8*>(wpL) = al;
        __syncthreads();
        if (k0 + 32 < K) loadA(k0 + 32, v);  // prefetch next tile while MFMAs run
        short8 fah = *reinterpret_cast<const short8*>(rpH);
        short8 fal = *reinterpret_cast<const short8*>(rpL);
#pragma unroll
        for (int m = 0; m < MC; ++m) {
            long wb = (long)(m * 16 + lr) * K + k0 + (lq << 3);
            short8 bh = *reinterpret_cast<const short8*>(Bhs + wb);
            short8 bl = *reinterpret_cast<const short8*>(Bls + wb);
            // D layout (verified): m = (lane>>4)*4+reg, n = lane&15
            acc[m] = __builtin_amdgcn_mfma_f32_16x16x32_bf16(bh, fah, acc[m], 0, 0, 0);
            acc[m] = __builtin_amdgcn_mfma_f32_16x16x32_bf16(bl, fah, acc[m], 0, 0, 0);
            acc[m] = __builtin_amdgcn_mfma_f32_16x16x32_bf16(bh, fal, acc[m], 0, 0, 0);
        }
    }

    int gn = n0 + (w << 4) + lr;
    if (gn < nrows) {
#pragma unroll
        for (int m = 0; m < MC; ++m) {
            int mb = m * 16 + (lq << 2);
            float o[4];
#pragma unroll
            for (int r = 0; r < 4; ++r) {
                o[r] = acc[m][r] + (bias ? bias[mb + r] : 0.f);
                if (ACT == 2) o[r] = fmaxf(o[r], 0.f);
            }
            store4(&out[(long)gn * M + mb], o);
        }
    }
}

// =============== CSR build (hist + scan + LDS-aggregated bucket scatter) ===============
__global__ void hist_all(const int* __restrict__ ei, int* __restrict__ cnt) {
    int p = blockIdx.y;
    int e = blockIdx.x * blockDim.x + threadIdx.x;
    if (e >= NE) return;
    int r = ei[((long)p * 2) * NE + e];
    atomicAdd(&cnt[(long)p * NN + r], 1);
}

// per-block sums of 256-chunks
__global__ void scan_pass1(const int* __restrict__ cnt, int* __restrict__ bsum) {
    int p = blockIdx.y, b = blockIdx.x, t = threadIdx.x;
    int idx = b * 256 + t;
    int v = (idx < NN) ? cnt[(long)p * NN + idx] : 0;
    __shared__ int sh[256];
    sh[t] = v;
    __syncthreads();
    for (int off = 128; off > 0; off >>= 1) {
        if (t < off) sh[t] += sh[t + off];
        __syncthreads();
    }
    if (t == 0) bsum[p * NSB + b] = sh[0];
}

// exclusive scan of the NSB block sums (one block per plane)
__global__ void scan_pass2(const int* __restrict__ bsum, int* __restrict__ boff) {
    int p = blockIdx.x, t = threadIdx.x;
    int v = (t < NSB) ? bsum[p * NSB + t] : 0;
    __shared__ int sh[256];
    sh[t] = v;
    __syncthreads();
    for (int off = 1; off < 256; off <<= 1) {
        int tmp = (t >= off) ? sh[t - off] : 0;
        __syncthreads();
        sh[t] += tmp;
        __syncthreads();
    }
    if (t < NSB) boff[p * NSB + t] = sh[t] - v;  // exclusive
}

// exclusive scan within block + block offset -> rowptr
__global__ void scan_pass3(const int* __restrict__ cnt, const int* __restrict__ boff,
                           int* __restrict__ rowptr) {
    int p = blockIdx.y, b = blockIdx.x, t = threadIdx.x;
    int idx = b * 256 + t;
    int v = (idx < NN) ? cnt[(long)p * NN + idx] : 0;
    __shared__ int sh[256];
    sh[t] = v;
    __syncthreads();
    for (int off = 1; off < 256; off <<= 1) {
        int tmp = (t >= off) ? sh[t - off] : 0;
        __syncthreads();
        sh[t] += tmp;
        __syncthreads();
    }
    int rp = boff[p * NSB + b] + sh[t] - v;
    if (idx < NN) rowptr[(long)p * NNR + idx] = rp;
    if (idx == NN - 1) rowptr[(long)p * NNR + NN] = rp + v;
}

// pass 1: LDS-aggregated bucket append. Each block owns EPB edges:
// LDS histogram -> ONE global atomicAdd per (block,bucket) (75K total, no
// serialization) -> write packed {row_off<<16|col, val} at bucket tails
// (~32 consecutive 8B entries per block-bucket = line-friendly runs).
__global__ __launch_bounds__(256) void bucket_append2(
    const int* __restrict__ ei, const float* __restrict__ ev,
    int* __restrict__ bcnt, int2* __restrict__ bbuf) {
    int p = blockIdx.y;
    int t = threadIdx.x;
    long e0 = (long)blockIdx.x * EPB;
    const int* rs = ei + ((long)p * 2) * NE;
    const int* cs = rs + NE;
    const float* vs = ev + (long)p * NE;
    __shared__ int lcnt[NBUK];
    __shared__ int lbase[NBUK];
    for (int b = t; b < NBUK; b += 256) lcnt[b] = 0;
    __syncthreads();
    for (int i = t; i < EPB; i += 256) {
        long e = e0 + i;
        if (e < NE) atomicAdd(&lcnt[rs[e] / BROWS], 1);
    }
    __syncthreads();
    for (int b = t; b < NBUK; b += 256) {
        int c = lcnt[b];
        lbase[b] = (c > 0) ? atomicAdd(&bcnt[p * NBUK + b], c) : 0;
        lcnt[b] = 0;
    }
    __syncthreads();
    for (int i = t; i < EPB; i += 256) {
        long e = e0 + i;
        if (e >= NE) continue;
        int r = rs[e];
        int b = r / BROWS;
        int off = atomicAdd(&lcnt[b], 1);
        int pos = lbase[b] + off;
        int meta = ((r - b * BROWS) << 16) | cs[e];  // col < 50000 < 2^16
        bbuf[((long)p * NBUK + b) * BCAP + pos] = make_int2(meta, __float_as_int(vs[e]));
    }
}

// pass 2: one workgroup per (bucket, plane); LDS row cursors; coalesced bbuf
// reads (no re-gather); CSR writes confined to a ~25KB span from ONE CU ->
// lines fully assembled in one XCD L2 before writeback.
__global__ __launch_bounds__(256) void bucket_scatter2(
    const int* __restrict__ bcnt, const int2* __restrict__ bbuf,
    const int* __restrict__ rowptr, int2* __restrict__ csr) {
    int b = blockIdx.x, p = blockIdx.y;
    int t = threadIdx.x;
    int row0 = b * BROWS;
    int nrows = min(BROWS, NN - row0);
    __shared__ int cur[BROWS];
    for (int i = t; i < nrows; i += 256) cur[i] = rowptr[(long)p * NNR + row0 + i];
    __syncthreads();
    int cntb = bcnt[p * NBUK + b];
    const int2* buf = bbuf + ((long)p * NBUK + b) * BCAP;
    int2* csrp = csr + (long)p * NE;
    for (int i = t; i < cntb; i += 256) {
        int2 ent = buf[i];
        int row_off = ent.x >> 16;
        int col = ent.x & 0xFFFF;
        int pos = atomicAdd(&cur[row_off], 1);
        csrp[pos] = make_int2(col, ent.y);
    }
}

// =============== fused dual gather SpMM (bf16x2 gathers, packed csr) ===============
// RPB rows per block, M/2 threads per row. ACT: 0 none, 1 telu.
template <int M, int ACT, int RPB>
__global__ void spmm_dual(const int* __restrict__ rowptr, const int2* __restrict__ csr,
                          const bf16* __restrict__ Ya, const bf16* __restrict__ Yb,
                          const float* __restrict__ biasA, const float* __restrict__ biasB,
                          float* __restrict__ outA, float* __restrict__ outB) {
    constexpr int TPR = M / 2;
    int t = threadIdx.x;
    int n = blockIdx.x * RPB + t / TPR;
    int hs = t % TPR;          // bf16x2 slot
    int h = hs * 2;            // column
    if (n >= NN) return;
    int e0 = rowptr[n], e1 = rowptr[n + 1];
    float aAl = biasA[h], aAh = biasA[h + 1];
    float aBl = biasB[h], aBh = biasB[h + 1];
    const unsigned* Ua = reinterpret_cast<const unsigned*>(Ya);
    const unsigned* Ub = reinterpret_cast<const unsigned*>(Yb);
    int e = e0;
    for (; e + 3 < e1; e += 4) {
        int2 p0 = csr[e], p1 = csr[e + 1], p2 = csr[e + 2], p3 = csr[e + 3];
        unsigned a0 = Ua[(long)p0.x * TPR + hs], a1 = Ua[(long)p1.x * TPR + hs];
        unsigned a2 = Ua[(long)p2.x * TPR + hs], a3 = Ua[(long)p3.x * TPR + hs];
        unsigned b0 = Ub[(long)p0.x * TPR + hs], b1 = Ub[(long)p1.x * TPR + hs];
        unsigned b2 = Ub[(long)p2.x * TPR + hs], b3 = Ub[(long)p3.x * TPR + hs];
        float v0 = __int_as_float(p0.y), v1 = __int_as_float(p1.y);
        float v2 = __int_as_float(p2.y), v3 = __int_as_float(p3.y);
        aAl += v0 * bf2f((short)a0) + v1 * bf2f((short)a1) + v2 * bf2f((short)a2) + v3 * bf2f((short)a3);
        aAh += v0 * bf2f((short)(a0 >> 16)) + v1 * bf2f((short)(a1 >> 16)) +
               v2 * bf2f((short)(a2 >> 16)) + v3 * bf2f((short)(a3 >> 16));
        aBl += v0 * bf2f((short)b0) + v1 * bf2f((short)b1) + v2 * bf2f((short)b2) + v3 * bf2f((short)b3);
        aBh += v0 * bf2f((short)(b0 >> 16)) + v1 * bf2f((short)(b1 >> 16)) +
               v2 * bf2f((short)(b2 >> 16)) + v3 * bf2f((short)(b3 >> 16));
    }
    for (; e < e1; ++e) {
        int2 pe = csr[e];
        float v = __int_as_float(pe.y);
        unsigned a = Ua[(long)pe.x * TPR + hs];
        unsigned b = Ub[(long)pe.x * TPR + hs];
        aAl += v * bf2f((short)a);
        aAh += v * bf2f((short)(a >> 16));
        aBl += v * bf2f((short)b);
        aBh += v * bf2f((short)(b >> 16));
    }
    if (ACT == 1) {
        aAl = telu_f(aAl); aAh = telu_f(aAh);
        aBl = telu_f(aBl); aBh = telu_f(aBh);
    }
    *reinterpret_cast<float2*>(&outA[(long)n * M + h]) = make_float2(aAl, aAh);
    *reinterpret_cast<float2*>(&outB[(long)n * M + h]) = make_float2(aBl, aBh);
}

// merged 3-plane spmm (bf16x2 gathers); 2 rows per 64-thread block
__global__ void spmm_merged(const int* __restrict__ rp0, const int2* __restrict__ cs0,
                            const int* __restrict__ rp1, const int2* __restrict__ cs1,
                            const int* __restrict__ rp2, const int2* __restrict__ cs2,
                            const bf16* __restrict__ Y, const float* __restrict__ wvec,
                            const float* __restrict__ bias, float* __restrict__ out) {
    constexpr int TPR = 32;
    int t = threadIdx.x;
    int n = blockIdx.x * 2 + t / TPR;
    int hs = t % TPR;
    int h = hs * 2;
    if (n >= NN) return;
    const int* rps[3] = {rp0, rp1, rp2};
    const int2* css[3] = {cs0, cs1, cs2};
    const unsigned* U = reinterpret_cast<const unsigned*>(Y);
    float al = 0.f, ah = 0.f;
#pragma unroll
    for (int p = 0; p < 3; ++p) {
        const int2* cs = css[p];
        int e0 = rps[p][n], e1 = rps[p][n + 1];
        float sl = 0.f, sh = 0.f;
        int e = e0;
        for (; e + 3 < e1; e += 4) {
            int2 p0 = cs[e], p1 = cs[e + 1], p2 = cs[e + 2], p3 = cs[e + 3];
            unsigned y0 = U[(long)p0.x * TPR + hs], y1 = U[(long)p1.x * TPR + hs];
            unsigned y2 = U[(long)p2.x * TPR + hs], y3 = U[(long)p3.x * TPR + hs];
            float v0 = __int_as_float(p0.y), v1 = __int_as_float(p1.y);
            float v2 = __int_as_float(p2.y), v3 = __int_as_float(p3.y);
            sl += v0 * bf2f((short)y0) + v1 * bf2f((short)y1) + v2 * bf2f((short)y2) + v3 * bf2f((short)y3);
            sh += v0 * bf2f((short)(y0 >> 16)) + v1 * bf2f((short)(y1 >> 16)) +
                  v2 * bf2f((short)(y2 >> 16)) + v3 * bf2f((short)(y3 >> 16));
        }
        for (; e < e1; ++e) {
            int2 pe = cs[e];
            unsigned y = U[(long)pe.x * TPR + hs];
            float v = __int_as_float(pe.y);
            sl += v * bf2f((short)y);
            sh += v * bf2f((short)(y >> 16));
        }
        float wv = wvec[p];
        al += wv * sl;
        ah += wv * sh;
    }
    *reinterpret_cast<float2*>(&out[(long)n * OUTD + h]) =
        make_float2(al + bias[h], ah + bias[h + 1]);
}

// =============== column summaries (coalesced, chunked) ===============
__global__ void colsum_passA(const float* __restrict__ spec, float* __restrict__ pmax,
                             float* __restrict__ psum, float* __restrict__ pexp) {
    int p = blockIdx.y, c = blockIdx.x;
    int t = threadIdx.x;
    int d = t & 63, rg = t >> 6;
    const float* base = spec + (long)p * NN * OUTD;
    int r0 = c * RC, r1 = min(r0 + RC, NN);
    float m = -INFINITY, s = 0.f, e = 0.f;
    for (int r = r0 + rg; r < r1; r += 4) {
        float v = base[(long)r * OUTD + d];
        s += v;
        if (v > m) { e = e * __expf(m - v) + 1.0f; m = v; }
        else e += __expf(v - m);
    }
    __shared__ float rm[256], rs[256], re[256];
    rm[t] = m; rs[t] = s; re[t] = e;
    __syncthreads();
    for (int off = 128; off >= 64; off >>= 1) {
        if (t < off) {
            float m2 = fmaxf(rm[t], rm[t + off]);
            re[t] = re[t] * __expf(rm[t] - m2) + re[t + off] * __expf(rm[t + off] - m2);
            rm[t] = m2;
            rs[t] = rs[t] + rs[t + off];
        }
        __syncthreads();
    }
    if (t < 64) {
        long idx = ((long)p * 64 + t) * NCH + c;
        pmax[idx] = rm[t]; psum[idx] = rs[t]; pexp[idx] = re[t];
    }
}

__global__ void colsum_reduceB(const float* __restrict__ pmax, const float* __restrict__ psum,
                               const float* __restrict__ pexp, float* __restrict__ ps,
                               float* __restrict__ zbuf) {
    int b = blockIdx.x;
    int p = b >> 6, d = b & 63;
    int t = threadIdx.x;
    long idx = (long)b * NCH + t;
    float m = pmax[idx], s = psum[idx], e = pexp[idx];
    for (int off = 32; off > 0; off >>= 1) {
        float m2 = fmaxf(m, __shfl_xor(m, off));
        e = e * __expf(m - m2) + __shfl_xor(e, off) * __expf(__shfl_xor(m, off) - m2);
        m = m2;
        s += __shfl_xor(s, off);
    }
    if (t == 0) {
        ps[p * 192 + d] = s / (float)NN;
        ps[p * 192 + 64 + d] = m;
        zbuf[b] = e;
    }
}

__global__ void colsum_passC(const float* __restrict__ spec, const float* __restrict__ ps,
                             const float* __restrict__ zbuf, float* __restrict__ pent) {
    int p = blockIdx.y, c = blockIdx.x;
    int t = threadIdx.x;
    int d = t & 63, rg = t >> 6;
    const float* base = spec + (long)p * NN * OUTD;
    float gm = ps[p * 192 + 64 + d];
    float zinv = 1.0f / zbuf[p * 64 + d];
    int r0 = c * RC, r1 = min(r0 + RC, NN);
    float ent = 0.f;
    for (int r = r0 + rg; r < r1; r += 4) {
        float v = base[(long)r * OUTD + d];
        float pv = __expf(v - gm) * zinv;
        ent -= pv * __logf(pv + 1e-6f);
    }
    __shared__ float rd[256];
    rd[t] = ent;
    __syncthreads();
    for (int off = 128; off >= 64; off >>= 1) {
        if (t < off) rd[t] += rd[t + off];
        __syncthreads();
    }
    if (t < 64) pent[((long)p * 64 + t) * NCH + c] = rd[t];
}

__global__ void colsum_reduceD(const float* __restrict__ pent, float* __restrict__ ps) {
    int b = blockIdx.x;
    int p = b >> 6, d = b & 63;
    int t = threadIdx.x;
    float e = pent[(long)b * NCH + t];
    for (int off = 32; off > 0; off >>= 1) e += __shfl_xor(e, off);
    if (t == 0) ps[p * 192 + 128 + d] = e;
}

// =============== walk + epilogue ===============
__global__ void walk_kernel(const float* __restrict__ ps, const float* __restrict__ weight_b,
                            const float* __restrict__ tau_p, float* __restrict__ wout) {
    if (threadIdx.x != 0 || blockIdx.x != 0) return;
    float sim[3][3];
    float inv = 1.0f / (sqrtf(192.0f) * tau_p[0]);
    for (int i = 0; i < 3; ++i)
        for (int j = 0; j < 3; ++j) {
            float dotv = 0.f;
            for (int k = 0; k < 192; ++k) dotv += ps[i * 192 + k] * ps[j * 192 + k];
            sim[i][j] = dotv * inv;
        }
    float T[3][3];
    for (int i = 0; i < 3; ++i) {
        float m = fmaxf(sim[i][0], fmaxf(sim[i][1], sim[i][2]));
        float e0 = expf(sim[i][0] - m), e1 = expf(sim[i][1] - m), e2 = expf(sim[i][2] - m);
        float s = e0 + e1 + e2;
        T[i][0] = e0 / s; T[i][1] = e1 / s; T[i][2] = e2 / s;
    }
    float b0 = weight_b[0], b1 = weight_b[1], b2 = weight_b[2];
    float m = fmaxf(b0, fmaxf(b1, b2));
    float e0 = expf(b0 - m), e1 = expf(b1 - m), e2 = expf(b2 - m);
    float s = e0 + e1 + e2;
    float pi0[3] = {e0 / s, e1 / s, e2 / s};
    float pi[3] = {pi0[0], pi0[1], pi0[2]};
    for (int it = 0; it < 13; ++it) {
        float n0 = pi[0] * T[0][0] + pi[1] * T[1][0] + pi[2] * T[2][0];
        float n1 = pi[0] * T[0][1] + pi[1] * T[1][1] + pi[2] * T[2][1];
        float n2 = pi[0] * T[0][2] + pi[1] * T[1][2] + pi[2] * T[2][2];
        pi[0] = 0.2f * pi0[0] + 0.8f * n0;
        pi[1] = 0.2f * pi0[1] + 0.8f * n1;
        pi[2] = 0.2f * pi0[2] + 0.8f * n2;
    }
    wout[0] = pi[0]; wout[1] = pi[1]; wout[2] = pi[2];
    float mm = fmaxf(pi[0], fmaxf(pi[1], pi[2]));
    float f0 = expf(pi[0] - mm), f1 = expf(pi[1] - mm), f2 = expf(pi[2] - mm);
    float fs = f0 + f1 + f2;
    wout[3] = f0 / fs; wout[4] = f1 / fs; wout[5] = f2 / fs;
}

__global__ void hraw_final(const float* __restrict__ U1, float* __restrict__ Hraw) {
    long i = (long)blockIdx.x * blockDim.x + threadIdx.x;
    if (i >= (long)NN * OUTD) return;
    Hraw[i] = 0.5f * (U1[i] + Hraw[i]);
}

extern "C" void kernel_launch(void* const* d_in, const int* in_sizes, int n_in,
                              void* d_out, int out_size, void* d_ws, size_t ws_size,
                              hipStream_t stream) {
    const float* feature   = (const float*)d_in[0];
    const int*   edge_index= (const int*)d_in[1];
    const float* edge_val  = (const float*)d_in[2];
    const float* spec_w1   = (const float*)d_in[3];
    const float* spec_b1   = (const float*)d_in[4];
    const float* spec_w2   = (const float*)d_in[5];
    const float* spec_b2   = (const float*)d_in[6];
    const float* shared_w1 = (const float*)d_in[7];
    const float* shared_b1 = (const float*)d_in[8];
    const float* shared_w2 = (const float*)d_in[9];
    const float* shared_b2 = (const float*)d_in[10];
    const float* weight_b  = (const float*)d_in[11];
    const float* tau       = (const float*)d_in[12];
    const float* mlp_w1    = (const float*)d_in[13];
    const float* mlp_b1    = (const float*)d_in[14];
    const float* mlp_w2    = (const float*)d_in[15];
    const float* mlp_b2    = (const float*)d_in[16];
    const float* raw_w1    = (const float*)d_in[17];
    const float* raw_b1    = (const float*)d_in[18];
    const float* raw_w2    = (const float*)d_in[19];
    const float* raw_b2    = (const float*)d_in[20];
    const float* proj_w    = (const float*)d_in[21];
    const float* proj_b    = (const float*)d_in[22];

    float* out        = (float*)d_out;
    float* spec_stack = out + (long)NN * OUTD;
    float* shr_stack  = spec_stack + 3L * NN * OUTD;
    float* Hcol       = out + 7L * NN * OUTD;
    float* Hraw       = out + 8L * NN * OUTD;

    // ---- workspace carve ----
    char* wp = (char*)d_ws;
    bf16* XWsp = (bf16*)wp; wp += (long)NN * 128 * sizeof(bf16);
    bf16* XWsh = (bf16*)wp; wp += (long)NN * 128 * sizeof(bf16);
    bf16* Bsp  = (bf16*)wp; wp += (long)NN * OUTD * sizeof(bf16);
    bf16* Bsh  = (bf16*)wp; wp += (long)NN * OUTD * sizeof(bf16);
    float* h1sp = (float*)wp; wp += (long)NN * 128 * sizeof(float);
    float* h1sh = (float*)wp; wp += (long)NN * 128 * sizeof(float);
    float* psBuf = (float*)wp; wp += 1024 * sizeof(float);
    float* wBuf  = (float*)wp; wp += 64 * sizeof(float);
    float* zBuf  = (float*)wp; wp += 256 * sizeof(float);
    float* pMax  = (float*)wp; wp += (long)3 * 64 * NCH * sizeof(float);
    float* pSum  = (float*)wp; wp += (long)3 * 64 * NCH * sizeof(float);
    float* pExp  = (float*)wp; wp += (long)3 * 64 * NCH * sizeof(float);
    float* pEnt  = (float*)wp; wp += (long)3 * 64 * NCH * sizeof(float);
    int2* csr_all = (int2*)wp;  wp += (long)NP * NE * sizeof(int2);
    int*  rowptr_all = (int*)wp; wp += (long)NP * NNR * sizeof(int) + 64;
    int* cnt    = (int*)wp; wp += (long)NP * NN * sizeof(int);
    int* bsum   = (int*)wp; wp += (long)NP * NSB * sizeof(int);
    int* boff   = (int*)wp; wp += (long)NP * NSB * sizeof(int);
    int* bcnt   = (int*)wp; wp += (long)NP * NBUK * sizeof(int);
    int2* bbuf  = (int2*)wp; wp += (long)NP * NBUK * BCAP * sizeof(int2);
    // pre-split transposed weights (bf16 hi/lo, [m][k] layout)
    bf16* w1sp_h = (bf16*)wp; wp += 3L * 256 * 128 * sizeof(bf16);
    bf16* w1sp_l = (bf16*)wp; wp += 3L * 256 * 128 * sizeof(bf16);
    bf16* w1sh_h = (bf16*)wp; wp += 256L * 128 * sizeof(bf16);
    bf16* w1sh_l = (bf16*)wp; wp += 256L * 128 * sizeof(bf16);
    bf16* w2sp_h = (bf16*)wp; wp += 3L * 128 * 64 * sizeof(bf16);
    bf16* w2sp_l = (bf16*)wp; wp += 3L * 128 * 64 * sizeof(bf16);
    bf16* w2sh_h = (bf16*)wp; wp += 128L * 64 * sizeof(bf16);
    bf16* w2sh_l = (bf16*)wp; wp += 128L * 64 * sizeof(bf16);
    bf16* mlp1_h = (bf16*)wp; wp += 192L * 128 * sizeof(bf16);
    bf16* mlp1_l = (bf16*)wp; wp += 192L * 128 * sizeof(bf16);
    bf16* mlp2_h = (bf16*)wp; wp += 128L * 64 * sizeof(bf16);
    bf16* mlp2_l = (bf16*)wp; wp += 128L * 64 * sizeof(bf16);
    bf16* raw1_h = (bf16*)wp; wp += 256L * 64 * sizeof(bf16);
    bf16* raw1_l = (bf16*)wp; wp += 256L * 64 * sizeof(bf16);
    bf16* raw2_h = (bf16*)wp; wp += 64L * 64 * sizeof(bf16);
    bf16* raw2_l = (bf16*)wp; wp += 64L * 64 * sizeof(bf16);
    bf16* proj_h = (bf16*)wp; wp += 256L * 64 * sizeof(bf16);
    bf16* proj_l = (bf16*)wp; wp += 256L * 64 * sizeof(bf16);

    int* rowptr[NP]; int2* csr[NP];
    for (int p = 0; p < NP; ++p) {
        rowptr[p] = rowptr_all + (long)p * NNR;
        csr[p]    = csr_all + (long)p * NE;
    }

    const int TB = 256;
    int g_rows = cdiv(NN, 64);  // 782

    // ---- weight prep (transpose + hi/lo split) ----
    transpose_split<<<cdiv(3L * 256 * 128, TB), TB, 0, stream>>>(spec_w1, w1sp_h, w1sp_l, 256, 128, 3L * 256 * 128);
    transpose_split<<<cdiv(256L * 128, TB), TB, 0, stream>>>(shared_w1, w1sh_h, w1sh_l, 256, 128, 256L * 128);
    transpose_split<<<cdiv(3L * 128 * 64, TB), TB, 0, stream>>>(spec_w2, w2sp_h, w2sp_l, 128, 64, 3L * 128 * 64);
    transpose_split<<<cdiv(128L * 64, TB), TB, 0, stream>>>(shared_w2, w2sh_h, w2sh_l, 128, 64, 128L * 64);
    transpose_split<<<cdiv(192L * 128, TB), TB, 0, stream>>>(mlp_w1, mlp1_h, mlp1_l, 192, 128, 192L * 128);
    transpose_split<<<cdiv(128L * 64, TB), TB, 0, stream>>>(mlp_w2, mlp2_h, mlp2_l, 128, 64, 128L * 64);
    transpose_split<<<cdiv(256L * 64, TB), TB, 0, stream>>>(raw_w1, raw1_h, raw1_l, 256, 64, 256L * 64);
    transpose_split<<<cdiv(64L * 64, TB), TB, 0, stream>>>(raw_w2, raw2_h, raw2_l, 64, 64, 64L * 64);
    transpose_split<<<cdiv(256L * 64, TB), TB, 0, stream>>>(proj_w, proj_h, proj_l, 256, 64, 256L * 64);

    // ---- build CSR (hist+scan, LDS-aggregated bucket scatter) ----
    hipMemsetAsync(cnt, 0, (long)NP * NN * sizeof(int), stream);
    hipMemsetAsync(bcnt, 0, (long)NP * NBUK * sizeof(int), stream);
    {
        dim3 gE(cdiv(NE, TB), NP);
        hist_all<<<gE, TB, 0, stream>>>(edge_index, cnt);
        dim3 gA(cdiv(NE, EPB), NP);
        bucket_append2<<<gA, 256, 0, stream>>>(edge_index, edge_val, bcnt, bbuf);
        dim3 gS(NSB, NP);
        scan_pass1<<<gS, 256, 0, stream>>>(cnt, bsum);
        scan_pass2<<<NP, 256, 0, stream>>>(bsum, boff);
        scan_pass3<<<gS, 256, 0, stream>>>(cnt, boff, rowptr_all);
        dim3 gB(NBUK, NP);
        bucket_scatter2<<<gB, 256, 0, stream>>>(bcnt, bbuf, rowptr_all, csr_all);
    }

    // ---- shared layer-1 GEMM (once) ----
    gemm_mfma<256, 128, 0, 0, bf16><<<g_rows, 256, 0, stream>>>(
        feature, w1sh_h, w1sh_l, nullptr, XWsh, NN, nullptr, nullptr, nullptr, nullptr);

    // ---- per plane: fused spec+shared pipeline ----
    for (int p = 0; p < NP; ++p) {
        gemm_mfma<256, 128, 0, 0, bf16><<<g_rows, 256, 0, stream>>>(
            feature, w1sp_h + (long)p * 256 * 128, w1sp_l + (long)p * 256 * 128,
            nullptr, XWsp, NN, nullptr, nullptr, nullptr, nullptr);
        spmm_dual<128, 1, 1><<<NN, 64, 0, stream>>>(rowptr[p], csr[p], XWsp, XWsh,
                                                    spec_b1 + (long)p * 128, shared_b1,
                                                    h1sp, h1sh);
        gemm_mfma<128, 64, 0, 0, bf16><<<g_rows, 256, 0, stream>>>(
            h1sp, w2sp_h + (long)p * 128 * 64, w2sp_l + (long)p * 128 * 64,
            nullptr, Bsp, NN, nullptr, nullptr, nullptr, nullptr);
        gemm_mfma<128, 64, 0, 0, bf16><<<g_rows, 256, 0, stream>>>(
            h1sh, w2sh_h, w2sh_l, nullptr, Bsh, NN, nullptr, nullptr, nullptr, nullptr);
        spmm_dual<64, 0, 2><<<cdiv(NN, 2), 64, 0, stream>>>(rowptr[p], csr[p], Bsp, Bsh,
                                                            spec_b2 + (long)p * 64, shared_b2,
                                                            spec_stack + (long)p * NN * OUTD,
                                                            shr_stack + (long)p * NN * OUTD);
    }

    // ---- summaries + random walk ----
    {
        dim3 gA(NCH, 3);
        colsum_passA<<<gA, 256, 0, stream>>>(spec_stack, pMax, pSum, pExp);
        colsum_reduceB<<<192, 64, 0, stream>>>(pMax, pSum, pExp, psBuf, zBuf);
        colsum_passC<<<gA, 256, 0, stream>>>(spec_stack, psBuf, zBuf, pEnt);
        colsum_reduceD<<<192, 64, 0, stream>>>(pEnt, psBuf);
    }
    walk_kernel<<<1, 64, 0, stream>>>(psBuf, weight_b, tau, wBuf);

    // ---- H_col (hidden reuses h1sp) ----
    gemm_mfma<192, 128, 1, 2, float><<<g_rows, 256, 0, stream>>>(
        spec_stack, mlp1_h, mlp1_l, mlp_b1, h1sp, NN, nullptr, nullptr, nullptr, nullptr);
    gemm_mfma<128, 64, 0, 0, float><<<g_rows, 256, 0, stream>>>(
        h1sp, mlp2_h, mlp2_l, mlp_b2, Hcol, NN, nullptr, nullptr, nullptr, nullptr);

    // ---- H_raw (U1 reuses h1sh; RB1/RB2 reuse Bsp/Bsh) ----
    float* U1 = h1sh;
    gemm_mfma<256, 64, 0, 0, bf16><<<g_rows, 256, 0, stream>>>(
        feature, raw1_h, raw1_l, nullptr, Bsp, NN, nullptr, nullptr, nullptr, nullptr);
    spmm_merged<<<cdiv(NN, 2), 64, 0, stream>>>(rowptr[0], csr[0],
                                                rowptr[1], csr[1],
                                                rowptr[2], csr[2],
                                                Bsp, wBuf, raw_b1, U1);
    gemm_mfma<64, 64, 0, 0, bf16><<<g_rows, 256, 0, stream>>>(
        U1, raw2_h, raw2_l, nullptr, Bsh, NN, nullptr, nullptr, nullptr, nullptr);
    spmm_merged<<<cdiv(NN, 2), 64, 0, stream>>>(rowptr[0], csr[0],
                                                rowptr[1], csr[1],
                                                rowptr[2], csr[2],
                                                Bsh, wBuf, raw_b2, Hraw);
    hraw_final<<<cdiv((long)NN * OUTD, TB), TB, 0, stream>>>(U1, Hraw);

    // ---- final projection (mix fused into A-loader) ----
    gemm_mfma<256, 64, 2, 0, float><<<g_rows, 256, 0, stream>>>(
        spec_stack, proj_h, proj_l, proj_b, out, NN, wBuf, shr_stack, Hcol, Hraw);
}

// Round 8
// 1407.416 us; speedup vs baseline: 1.6809x; 1.0750x over previous
//
#include <hip/hip_runtime.h>
#include <hip/hip_bf16.h>
#include <math.h>

#define NN 50000
#define NFEAT 256
#define NHID 128
#define OUTD 64
#define NE 800000
#define NP 3
#define NCH 64
#define RC 782   // ceil(NN/NCH)
#define NNR (NN + 1)  // rowptr stride per plane
#define NBUK 256
#define BROWS 196   // ceil(NN/NBUK)
#define BCAP 4096   // mean bucket = 3136, +17 sigma
#define EPB 8192    // edges per append block

typedef __hip_bfloat16 bf16;
typedef __attribute__((ext_vector_type(8))) short short8;
typedef __attribute__((ext_vector_type(4))) short short4v;
typedef __attribute__((ext_vector_type(4))) float f32x4;
typedef unsigned long long u64;

static inline int cdiv(long a, long b) { return (int)((a + b - 1) / b); }

// RNE f32 -> bf16 bits (finite inputs only)
__device__ __forceinline__ short f2bf(float x) {
    unsigned u = __builtin_bit_cast(unsigned, x);
    unsigned r = (u + 0x7FFFu + ((u >> 16) & 1u)) >> 16;
    return (short)r;
}
__device__ __forceinline__ float bf2f(short b) {
    unsigned u = ((unsigned)(unsigned short)b) << 16;
    return __builtin_bit_cast(float, u);
}

__device__ __forceinline__ float telu_f(float x) {
    float e = __expf(x);
    float t = __expf(-2.0f * e);
    return x * (1.0f - t) / (1.0f + t);
}

__device__ __forceinline__ void ld8(const float* __restrict__ p, float v[8]) {
    float4 a = *reinterpret_cast<const float4*>(p);
    float4 b = *reinterpret_cast<const float4*>(p + 4);
    v[0] = a.x; v[1] = a.y; v[2] = a.z; v[3] = a.w;
    v[4] = b.x; v[5] = b.y; v[6] = b.z; v[7] = b.w;
}

__device__ __forceinline__ void store4(float* p, const float o[4]) {
    *reinterpret_cast<float4*>(p) = make_float4(o[0], o[1], o[2], o[3]);
}
__device__ __forceinline__ void store4(bf16* p, const float o[4]) {
    short4v u;
    u[0] = f2bf(o[0]); u[1] = f2bf(o[1]); u[2] = f2bf(o[2]); u[3] = f2bf(o[3]);
    *reinterpret_cast<short4v*>(p) = u;
}

// =============== weight prep: transpose + hi/lo bf16 split ===============
// src: (P,K,M) f32 row-major -> dh/dl: (P,M,K) bf16
__global__ void transpose_split(const float* __restrict__ src, bf16* __restrict__ dh,
                                bf16* __restrict__ dl, int K, int M, long total) {
    long idx = (long)blockIdx.x * blockDim.x + threadIdx.x;
    if (idx >= total) return;
    long pm = idx / K;
    int k = (int)(idx - pm * K);
    long p = pm / M;
    int m = (int)(pm - p * M);
    float v = src[(p * K + k) * M + m];
    short hb = f2bf(v);
    short lb = f2bf(v - bf2f(hb));
    reinterpret_cast<short*>(dh)[idx] = hb;
    reinterpret_cast<short*>(dl)[idx] = lb;
}

// =============== MFMA GEMM ===============
// out[n, m] = sum_k A[n,k] * B[k,m]  (B pre-transposed/split: Bh/Bl are [m][k] bf16)
// BM=64 rows/block, 4 waves x 16 rows, BK=32. hi/lo split on BOTH operands
// (3 MFMAs: ah*bh + ah*bl + al*bh) => f32-equivalent accuracy.
// MODE: 0 plain A[n*K+k]; 1 concat3 planes (spec_stack, K=192); 2 final mix (K=256)
// ACT: 0 none, 2 relu. OT: float or bf16.
template <int K, int M, int MODE, int ACT, typename OT>
__global__ __launch_bounds__(256) void gemm_mfma(
    const float* __restrict__ A, const bf16* __restrict__ Bh, const bf16* __restrict__ Bl,
    const float* __restrict__ bias, OT* __restrict__ out, int nrows,
    const float* __restrict__ wvec, const float* __restrict__ s1,
    const float* __restrict__ s2, const float* __restrict__ s3) {
    constexpr int MC = M / 16;
    __shared__ short AsH[64 * 32];
    __shared__ short AsL[64 * 32];

    int t = threadIdx.x;
    int n0 = blockIdx.x * 64;
    int w = t >> 6;
    int l = t & 63;
    int lr = l & 15, lq = l >> 4;

    float w0 = 0.f, w1 = 0.f, w2 = 0.f;
    if (MODE == 2) { w0 = wvec[3]; w1 = wvec[4]; w2 = wvec[5]; }

    f32x4 acc[MC];
#pragma unroll
    for (int i = 0; i < MC; ++i) {
        f32x4 z = {0.f, 0.f, 0.f, 0.f};
        acc[i] = z;
    }

    // staging coords: 256 threads cover 64 rows x 32 k; row = t>>2, 8-elem chunk = t&3
    int sr = t >> 2, sc = t & 3;
    int gn_s = n0 + sr;
    int wslot = (sc ^ ((sr >> 2) & 3)) << 3;   // XOR-swizzled 16B slot
    short* wpH = &AsH[sr * 32 + wslot];
    short* wpL = &AsL[sr * 32 + wslot];

    // fragment-read coords: wave w owns rows [w*16, w*16+16)
    int rrow = (w << 4) + lr;
    int roff = rrow * 32 + ((lq ^ ((rrow >> 2) & 3)) << 3);
    const short* rpH = &AsH[roff];
    const short* rpL = &AsL[roff];

    const short* Bhs = reinterpret_cast<const short*>(Bh);
    const short* Bls = reinterpret_cast<const short*>(Bl);

    auto loadA = [&](int k0, float v[8]) {
        if (gn_s >= nrows) {
#pragma unroll
            for (int j = 0; j < 8; ++j) v[j] = 0.f;
            return;
        }
        if (MODE == 0) {
            ld8(A + (long)gn_s * K + k0 + sc * 8, v);
        } else if (MODE == 1) {
            int plane = k0 >> 6;
            int d = (k0 & 63) + sc * 8;
            ld8(A + ((long)plane * NN + gn_s) * OUTD + d, v);
        } else {
            int seg = k0 >> 6;
            int d = (k0 & 63) + sc * 8;
            if (seg == 0) {
                float x0[8], x1[8], x2[8];
                ld8(A + ((long)0 * NN + gn_s) * OUTD + d, x0);
                ld8(A + ((long)1 * NN + gn_s) * OUTD + d, x1);
                ld8(A + ((long)2 * NN + gn_s) * OUTD + d, x2);
#pragma unroll
                for (int j = 0; j < 8; ++j) v[j] = w0 * x0[j] + w1 * x1[j] + w2 * x2[j];
            } else if (seg == 1) {
                float x0[8], x1[8], x2[8];
                ld8(s1 + ((long)0 * NN + gn_s) * OUTD + d, x0);
                ld8(s1 + ((long)1 * NN + gn_s) * OUTD + d, x1);
                ld8(s1 + ((long)2 * NN + gn_s) * OUTD + d, x2);
#pragma unroll
                for (int j = 0; j < 8; ++j) v[j] = (x0[j] + x1[j] + x2[j]) * (1.0f / 3.0f);
            } else if (seg == 2) {
                ld8(s2 + (long)gn_s * OUTD + d, v);
            } else {
                ld8(s3 + (long)gn_s * OUTD + d, v);
            }
        }
    };

    float v[8];
    loadA(0, v);
    for (int k0 = 0; k0 < K; k0 += 32) {
        short8 ah, al;
#pragma unroll
        for (int j = 0; j < 8; ++j) {
            short hb = f2bf(v[j]);
            ah[j] = hb;
            al[j] = f2bf(v[j] - bf2f(hb));
        }
        __syncthreads();  // previous iter's fragment reads done
        *reinterpret_cast<short8*>(wpH) = ah;
        *reinterpret_cast<short8*>(wpL) = al;
        __syncthreads();
        if (k0 + 32 < K) loadA(k0 + 32, v);  // prefetch next tile while MFMAs run
        short8 fah = *reinterpret_cast<const short8*>(rpH);
        short8 fal = *reinterpret_cast<const short8*>(rpL);
#pragma unroll
        for (int m = 0; m < MC; ++m) {
            long wb = (long)(m * 16 + lr) * K + k0 + (lq << 3);
            short8 bh = *reinterpret_cast<const short8*>(Bhs + wb);
            short8 bl = *reinterpret_cast<const short8*>(Bls + wb);
            // D layout (verified): m = (lane>>4)*4+reg, n = lane&15
            acc[m] = __builtin_amdgcn_mfma_f32_16x16x32_bf16(bh, fah, acc[m], 0, 0, 0);
            acc[m] = __builtin_amdgcn_mfma_f32_16x16x32_bf16(bl, fah, acc[m], 0, 0, 0);
            acc[m] = __builtin_amdgcn_mfma_f32_16x16x32_bf16(bh, fal, acc[m], 0, 0, 0);
        }
    }

    int gn = n0 + (w << 4) + lr;
    if (gn < nrows) {
#pragma unroll
        for (int m = 0; m < MC; ++m) {
            int mb = m * 16 + (lq << 2);
            float o[4];
#pragma unroll
            for (int r = 0; r < 4; ++r) {
                o[r] = acc[m][r] + (bias ? bias[mb + r] : 0.f);
                if (ACT == 2) o[r] = fmaxf(o[r], 0.f);
            }
            store4(&out[(long)gn * M + mb], o);
        }
    }
}

// =============== CSR build (bucket append + bucket-local hist/scan/scatter) ===============
// pass 1: LDS-aggregated bucket append. Each block owns EPB edges:
// LDS histogram -> ONE global atomicAdd per (block,bucket) (75K total) ->
// write packed {row_off<<16|col, val} at bucket tails (line-friendly runs).
__global__ __launch_bounds__(256) void bucket_append2(
    const int* __restrict__ ei, const float* __restrict__ ev,
    int* __restrict__ bcnt, int2* __restrict__ bbuf) {
    int p = blockIdx.y;
    int t = threadIdx.x;
    long e0 = (long)blockIdx.x * EPB;
    const int* rs = ei + ((long)p * 2) * NE;
    const int* cs = rs + NE;
    const float* vs = ev + (long)p * NE;
    __shared__ int lcnt[NBUK];
    __shared__ int lbase[NBUK];
    for (int b = t; b < NBUK; b += 256) lcnt[b] = 0;
    __syncthreads();
    for (int i = t; i < EPB; i += 256) {
        long e = e0 + i;
        if (e < NE) atomicAdd(&lcnt[rs[e] / BROWS], 1);
    }
    __syncthreads();
    for (int b = t; b < NBUK; b += 256) {
        int c = lcnt[b];
        lbase[b] = (c > 0) ? atomicAdd(&bcnt[p * NBUK + b], c) : 0;
        lcnt[b] = 0;
    }
    __syncthreads();
    for (int i = t; i < EPB; i += 256) {
        long e = e0 + i;
        if (e >= NE) continue;
        int r = rs[e];
        int b = r / BROWS;
        int off = atomicAdd(&lcnt[b], 1);
        int pos = lbase[b] + off;
        int meta = ((r - b * BROWS) << 16) | cs[e];  // col < 50000 < 2^16
        bbuf[((long)p * NBUK + b) * BCAP + pos] = make_int2(meta, __float_as_int(vs[e]));
    }
}

// exclusive scan of per-bucket totals -> global bucket base offsets (one block/plane)
__global__ void scan_bcnt(const int* __restrict__ bcnt, int* __restrict__ bbase) {
    int p = blockIdx.x, t = threadIdx.x;
    int v = bcnt[p * NBUK + t];
    __shared__ int sh[NBUK];
    sh[t] = v;
    __syncthreads();
    for (int off = 1; off < NBUK; off <<= 1) {
        int tmp = (t >= off) ? sh[t - off] : 0;
        __syncthreads();
        sh[t] += tmp;
        __syncthreads();
    }
    bbase[p * NBUK + t] = sh[t] - v;  // exclusive
}

// pass 2: one workgroup per (bucket, plane). Derives rowptr for its row range
// from an LDS histogram of its own bbuf entries (no device-scope atomics),
// then scatters; CSR writes confined to a ~25KB span from ONE CU.
__global__ __launch_bounds__(256) void bucket_scatter3(
    const int* __restrict__ bcnt, const int* __restrict__ bbase,
    const int2* __restrict__ bbuf, int* __restrict__ rowptr, int2* __restrict__ csr) {
    int b = blockIdx.x, p = blockIdx.y;
    int t = threadIdx.x;
    int row0 = b * BROWS;
    int nrows = min(BROWS, NN - row0);
    int cntb = bcnt[p * NBUK + b];
    int base = bbase[p * NBUK + b];
    const int2* buf = bbuf + ((long)p * NBUK + b) * BCAP;
    __shared__ int rcnt[256];
    __shared__ int cur[BROWS];
    rcnt[t] = 0;
    __syncthreads();
    // LDS row histogram of this bucket's edges (coalesced reads)
    for (int i = t; i < cntb; i += 256) atomicAdd(&rcnt[buf[i].x >> 16], 1);
    __syncthreads();
    // exclusive scan over the 196 row counters (padded to 256)
    int v = rcnt[t];
    __shared__ int sh[256];
    sh[t] = v;
    __syncthreads();
    for (int off = 1; off < 256; off <<= 1) {
        int tmp = (t >= off) ? sh[t - off] : 0;
        __syncthreads();
        sh[t] += tmp;
        __syncthreads();
    }
    int excl = base + sh[t] - v;
    if (t < nrows) {
        rowptr[(long)p * NNR + row0 + t] = excl;
        cur[t] = excl;
    }
    if (b == NBUK - 1 && t == 0) rowptr[(long)p * NNR + NN] = base + cntb;
    __syncthreads();
    // scatter
    int2* csrp = csr + (long)p * NE;
    for (int i = t; i < cntb; i += 256) {
        int2 ent = buf[i];
        int row_off = ent.x >> 16;
        int col = ent.x & 0xFFFF;
        int pos = atomicAdd(&cur[row_off], 1);
        csrp[pos] = make_int2(col, ent.y);
    }
}

// =============== fused dual gather SpMM (bf16x2 gathers, packed csr) ===============
// RPB rows per block, M/2 threads per row. ACT: 0 none, 1 telu.
template <int M, int ACT, int RPB>
__global__ void spmm_dual(const int* __restrict__ rowptr, const int2* __restrict__ csr,
                          const bf16* __restrict__ Ya, const bf16* __restrict__ Yb,
                          const float* __restrict__ biasA, const float* __restrict__ biasB,
                          float* __restrict__ outA, float* __restrict__ outB) {
    constexpr int TPR = M / 2;
    int t = threadIdx.x;
    int n = blockIdx.x * RPB + t / TPR;
    int hs = t % TPR;          // bf16x2 slot
    int h = hs * 2;            // column
    if (n >= NN) return;
    int e0 = rowptr[n], e1 = rowptr[n + 1];
    float aAl = biasA[h], aAh = biasA[h + 1];
    float aBl = biasB[h], aBh = biasB[h + 1];
    const unsigned* Ua = reinterpret_cast<const unsigned*>(Ya);
    const unsigned* Ub = reinterpret_cast<const unsigned*>(Yb);
    int e = e0;
    for (; e + 3 < e1; e += 4) {
        int2 p0 = csr[e], p1 = csr[e + 1], p2 = csr[e + 2], p3 = csr[e + 3];
        unsigned a0 = Ua[(long)p0.x * TPR + hs], a1 = Ua[(long)p1.x * TPR + hs];
        unsigned a2 = Ua[(long)p2.x * TPR + hs], a3 = Ua[(long)p3.x * TPR + hs];
        unsigned b0 = Ub[(long)p0.x * TPR + hs], b1 = Ub[(long)p1.x * TPR + hs];
        unsigned b2 = Ub[(long)p2.x * TPR + hs], b3 = Ub[(long)p3.x * TPR + hs];
        float v0 = __int_as_float(p0.y), v1 = __int_as_float(p1.y);
        float v2 = __int_as_float(p2.y), v3 = __int_as_float(p3.y);
        aAl += v0 * bf2f((short)a0) + v1 * bf2f((short)a1) + v2 * bf2f((short)a2) + v3 * bf2f((short)a3);
        aAh += v0 * bf2f((short)(a0 >> 16)) + v1 * bf2f((short)(a1 >> 16)) +
               v2 * bf2f((short)(a2 >> 16)) + v3 * bf2f((short)(a3 >> 16));
        aBl += v0 * bf2f((short)b0) + v1 * bf2f((short)b1) + v2 * bf2f((short)b2) + v3 * bf2f((short)b3);
        aBh += v0 * bf2f((short)(b0 >> 16)) + v1 * bf2f((short)(b1 >> 16)) +
               v2 * bf2f((short)(b2 >> 16)) + v3 * bf2f((short)(b3 >> 16));
    }
    for (; e < e1; ++e) {
        int2 pe = csr[e];
        float v = __int_as_float(pe.y);
        unsigned a = Ua[(long)pe.x * TPR + hs];
        unsigned b = Ub[(long)pe.x * TPR + hs];
        aAl += v * bf2f((short)a);
        aAh += v * bf2f((short)(a >> 16));
        aBl += v * bf2f((short)b);
        aBh += v * bf2f((short)(b >> 16));
    }
    if (ACT == 1) {
        aAl = telu_f(aAl); aAh = telu_f(aAh);
        aBl = telu_f(aBl); aBh = telu_f(aBh);
    }
    *reinterpret_cast<float2*>(&outA[(long)n * M + h]) = make_float2(aAl, aAh);
    *reinterpret_cast<float2*>(&outB[(long)n * M + h]) = make_float2(aBl, aBh);
}

// merged 3-plane spmm (bf16x2 gathers); 2 rows per 64-thread block
__global__ void spmm_merged(const int* __restrict__ rp0, const int2* __restrict__ cs0,
                            const int* __restrict__ rp1, const int2* __restrict__ cs1,
                            const int* __restrict__ rp2, const int2* __restrict__ cs2,
                            const bf16* __restrict__ Y, const float* __restrict__ wvec,
                            const float* __restrict__ bias, float* __restrict__ out) {
    constexpr int TPR = 32;
    int t = threadIdx.x;
    int n = blockIdx.x * 2 + t / TPR;
    int hs = t % TPR;
    int h = hs * 2;
    if (n >= NN) return;
    const int* rps[3] = {rp0, rp1, rp2};
    const int2* css[3] = {cs0, cs1, cs2};
    const unsigned* U = reinterpret_cast<const unsigned*>(Y);
    float al = 0.f, ah = 0.f;
#pragma unroll
    for (int p = 0; p < 3; ++p) {
        const int2* cs = css[p];
        int e0 = rps[p][n], e1 = rps[p][n + 1];
        float sl = 0.f, sh = 0.f;
        int e = e0;
        for (; e + 3 < e1; e += 4) {
            int2 p0 = cs[e], p1 = cs[e + 1], p2 = cs[e + 2], p3 = cs[e + 3];
            unsigned y0 = U[(long)p0.x * TPR + hs], y1 = U[(long)p1.x * TPR + hs];
            unsigned y2 = U[(long)p2.x * TPR + hs], y3 = U[(long)p3.x * TPR + hs];
            float v0 = __int_as_float(p0.y), v1 = __int_as_float(p1.y);
            float v2 = __int_as_float(p2.y), v3 = __int_as_float(p3.y);
            sl += v0 * bf2f((short)y0) + v1 * bf2f((short)y1) + v2 * bf2f((short)y2) + v3 * bf2f((short)y3);
            sh += v0 * bf2f((short)(y0 >> 16)) + v1 * bf2f((short)(y1 >> 16)) +
                  v2 * bf2f((short)(y2 >> 16)) + v3 * bf2f((short)(y3 >> 16));
        }
        for (; e < e1; ++e) {
            int2 pe = cs[e];
            unsigned y = U[(long)pe.x * TPR + hs];
            float v = __int_as_float(pe.y);
            sl += v * bf2f((short)y);
            sh += v * bf2f((short)(y >> 16));
        }
        float wv = wvec[p];
        al += wv * sl;
        ah += wv * sh;
    }
    *reinterpret_cast<float2*>(&out[(long)n * OUTD + h]) =
        make_float2(al + bias[h], ah + bias[h + 1]);
}

// =============== column summaries (coalesced, chunked) ===============
__global__ void colsum_passA(const float* __restrict__ spec, float* __restrict__ pmax,
                             float* __restrict__ psum, float* __restrict__ pexp) {
    int p = blockIdx.y, c = blockIdx.x;
    int t = threadIdx.x;
    int d = t & 63, rg = t >> 6;
    const float* base = spec + (long)p * NN * OUTD;
    int r0 = c * RC, r1 = min(r0 + RC, NN);
    float m = -INFINITY, s = 0.f, e = 0.f;
    for (int r = r0 + rg; r < r1; r += 4) {
        float v = base[(long)r * OUTD + d];
        s += v;
        if (v > m) { e = e * __expf(m - v) + 1.0f; m = v; }
        else e += __expf(v - m);
    }
    __shared__ float rm[256], rs[256], re[256];
    rm[t] = m; rs[t] = s; re[t] = e;
    __syncthreads();
    for (int off = 128; off >= 64; off >>= 1) {
        if (t < off) {
            float m2 = fmaxf(rm[t], rm[t + off]);
            re[t] = re[t] * __expf(rm[t] - m2) + re[t + off] * __expf(rm[t + off] - m2);
            rm[t] = m2;
            rs[t] = rs[t] + rs[t + off];
        }
        __syncthreads();
    }
    if (t < 64) {
        long idx = ((long)p * 64 + t) * NCH + c;
        pmax[idx] = rm[t]; psum[idx] = rs[t]; pexp[idx] = re[t];
    }
}

__global__ void colsum_reduceB(const float* __restrict__ pmax, const float* __restrict__ psum,
                               const float* __restrict__ pexp, float* __restrict__ ps,
                               float* __restrict__ zbuf) {
    int b = blockIdx.x;
    int p = b >> 6, d = b & 63;
    int t = threadIdx.x;
    long idx = (long)b * NCH + t;
    float m = pmax[idx], s = psum[idx], e = pexp[idx];
    for (int off = 32; off > 0; off >>= 1) {
        float m2 = fmaxf(m, __shfl_xor(m, off));
        e = e * __expf(m - m2) + __shfl_xor(e, off) * __expf(__shfl_xor(m, off) - m2);
        m = m2;
        s += __shfl_xor(s, off);
    }
    if (t == 0) {
        ps[p * 192 + d] = s / (float)NN;
        ps[p * 192 + 64 + d] = m;
        zbuf[b] = e;
    }
}

__global__ void colsum_passC(const float* __restrict__ spec, const float* __restrict__ ps,
                             const float* __restrict__ zbuf, float* __restrict__ pent) {
    int p = blockIdx.y, c = blockIdx.x;
    int t = threadIdx.x;
    int d = t & 63, rg = t >> 6;
    const float* base = spec + (long)p * NN * OUTD;
    float gm = ps[p * 192 + 64 + d];
    float zinv = 1.0f / zbuf[p * 64 + d];
    int r0 = c * RC, r1 = min(r0 + RC, NN);
    float ent = 0.f;
    for (int r = r0 + rg; r < r1; r += 4) {
        float v = base[(long)r * OUTD + d];
        float pv = __expf(v - gm) * zinv;
        ent -= pv * __logf(pv + 1e-6f);
    }
    __shared__ float rd[256];
    rd[t] = ent;
    __syncthreads();
    for (int off = 128; off >= 64; off >>= 1) {
        if (t < off) rd[t] += rd[t + off];
        __syncthreads();
    }
    if (t < 64) pent[((long)p * 64 + t) * NCH + c] = rd[t];
}

__global__ void colsum_reduceD(const float* __restrict__ pent, float* __restrict__ ps) {
    int b = blockIdx.x;
    int p = b >> 6, d = b & 63;
    int t = threadIdx.x;
    float e = pent[(long)b * NCH + t];
    for (int off = 32; off > 0; off >>= 1) e += __shfl_xor(e, off);
    if (t == 0) ps[p * 192 + 128 + d] = e;
}

// =============== walk + epilogue ===============
__global__ void walk_kernel(const float* __restrict__ ps, const float* __restrict__ weight_b,
                            const float* __restrict__ tau_p, float* __restrict__ wout) {
    if (threadIdx.x != 0 || blockIdx.x != 0) return;
    float sim[3][3];
    float inv = 1.0f / (sqrtf(192.0f) * tau_p[0]);
    for (int i = 0; i < 3; ++i)
        for (int j = 0; j < 3; ++j) {
            float dotv = 0.f;
            for (int k = 0; k < 192; ++k) dotv += ps[i * 192 + k] * ps[j * 192 + k];
            sim[i][j] = dotv * inv;
        }
    float T[3][3];
    for (int i = 0; i < 3; ++i) {
        float m = fmaxf(sim[i][0], fmaxf(sim[i][1], sim[i][2]));
        float e0 = expf(sim[i][0] - m), e1 = expf(sim[i][1] - m), e2 = expf(sim[i][2] - m);
        float s = e0 + e1 + e2;
        T[i][0] = e0 / s; T[i][1] = e1 / s; T[i][2] = e2 / s;
    }
    float b0 = weight_b[0], b1 = weight_b[1], b2 = weight_b[2];
    float m = fmaxf(b0, fmaxf(b1, b2));
    float e0 = expf(b0 - m), e1 = expf(b1 - m), e2 = expf(b2 - m);
    float s = e0 + e1 + e2;
    float pi0[3] = {e0 / s, e1 / s, e2 / s};
    float pi[3] = {pi0[0], pi0[1], pi0[2]};
    for (int it = 0; it < 13; ++it) {
        float n0 = pi[0] * T[0][0] + pi[1] * T[1][0] + pi[2] * T[2][0];
        float n1 = pi[0] * T[0][1] + pi[1] * T[1][1] + pi[2] * T[2][1];
        float n2 = pi[0] * T[0][2] + pi[1] * T[1][2] + pi[2] * T[2][2];
        pi[0] = 0.2f * pi0[0] + 0.8f * n0;
        pi[1] = 0.2f * pi0[1] + 0.8f * n1;
        pi[2] = 0.2f * pi0[2] + 0.8f * n2;
    }
    wout[0] = pi[0]; wout[1] = pi[1]; wout[2] = pi[2];
    float mm = fmaxf(pi[0], fmaxf(pi[1], pi[2]));
    float f0 = expf(pi[0] - mm), f1 = expf(pi[1] - mm), f2 = expf(pi[2] - mm);
    float fs = f0 + f1 + f2;
    wout[3] = f0 / fs; wout[4] = f1 / fs; wout[5] = f2 / fs;
}

__global__ void hraw_final(const float* __restrict__ U1, float* __restrict__ Hraw) {
    long i = (long)blockIdx.x * blockDim.x + threadIdx.x;
    if (i >= (long)NN * OUTD) return;
    Hraw[i] = 0.5f * (U1[i] + Hraw[i]);
}

extern "C" void kernel_launch(void* const* d_in, const int* in_sizes, int n_in,
                              void* d_out, int out_size, void* d_ws, size_t ws_size,
                              hipStream_t stream) {
    const float* feature   = (const float*)d_in[0];
    const int*   edge_index= (const int*)d_in[1];
    const float* edge_val  = (const float*)d_in[2];
    const float* spec_w1   = (const float*)d_in[3];
    const float* spec_b1   = (const float*)d_in[4];
    const float* spec_w2   = (const float*)d_in[5];
    const float* spec_b2   = (const float*)d_in[6];
    const float* shared_w1 = (const float*)d_in[7];
    const float* shared_b1 = (const float*)d_in[8];
    const float* shared_w2 = (const float*)d_in[9];
    const float* shared_b2 = (const float*)d_in[10];
    const float* weight_b  = (const float*)d_in[11];
    const float* tau       = (const float*)d_in[12];
    const float* mlp_w1    = (const float*)d_in[13];
    const float* mlp_b1    = (const float*)d_in[14];
    const float* mlp_w2    = (const float*)d_in[15];
    const float* mlp_b2    = (const float*)d_in[16];
    const float* raw_w1    = (const float*)d_in[17];
    const float* raw_b1    = (const float*)d_in[18];
    const float* raw_w2    = (const float*)d_in[19];
    const float* raw_b2    = (const float*)d_in[20];
    const float* proj_w    = (const float*)d_in[21];
    const float* proj_b    = (const float*)d_in[22];

    float* out        = (float*)d_out;
    float* spec_stack = out + (long)NN * OUTD;
    float* shr_stack  = spec_stack + 3L * NN * OUTD;
    float* Hcol       = out + 7L * NN * OUTD;
    float* Hraw       = out + 8L * NN * OUTD;

    // ---- workspace carve ----
    char* wp = (char*)d_ws;
    bf16* XWsp = (bf16*)wp; wp += (long)NN * 128 * sizeof(bf16);
    bf16* XWsh = (bf16*)wp; wp += (long)NN * 128 * sizeof(bf16);
    bf16* Bsp  = (bf16*)wp; wp += (long)NN * OUTD * sizeof(bf16);
    bf16* Bsh  = (bf16*)wp; wp += (long)NN * OUTD * sizeof(bf16);
    float* h1sp = (float*)wp; wp += (long)NN * 128 * sizeof(float);
    float* h1sh = (float*)wp; wp += (long)NN * 128 * sizeof(float);
    float* psBuf = (float*)wp; wp += 1024 * sizeof(float);
    float* wBuf  = (float*)wp; wp += 64 * sizeof(float);
    float* zBuf  = (float*)wp; wp += 256 * sizeof(float);
    float* pMax  = (float*)wp; wp += (long)3 * 64 * NCH * sizeof(float);
    float* pSum  = (float*)wp; wp += (long)3 * 64 * NCH * sizeof(float);
    float* pExp  = (float*)wp; wp += (long)3 * 64 * NCH * sizeof(float);
    float* pEnt  = (float*)wp; wp += (long)3 * 64 * NCH * sizeof(float);
    int2* csr_all = (int2*)wp;  wp += (long)NP * NE * sizeof(int2);
    int*  rowptr_all = (int*)wp; wp += (long)NP * NNR * sizeof(int) + 64;
    int* bcnt   = (int*)wp; wp += (long)NP * NBUK * sizeof(int);
    int* bbase  = (int*)wp; wp += (long)NP * NBUK * sizeof(int);
    int2* bbuf  = (int2*)wp; wp += (long)NP * NBUK * BCAP * sizeof(int2);
    // pre-split transposed weights (bf16 hi/lo, [m][k] layout)
    bf16* w1sp_h = (bf16*)wp; wp += 3L * 256 * 128 * sizeof(bf16);
    bf16* w1sp_l = (bf16*)wp; wp += 3L * 256 * 128 * sizeof(bf16);
    bf16* w1sh_h = (bf16*)wp; wp += 256L * 128 * sizeof(bf16);
    bf16* w1sh_l = (bf16*)wp; wp += 256L * 128 * sizeof(bf16);
    bf16* w2sp_h = (bf16*)wp; wp += 3L * 128 * 64 * sizeof(bf16);
    bf16* w2sp_l = (bf16*)wp; wp += 3L * 128 * 64 * sizeof(bf16);
    bf16* w2sh_h = (bf16*)wp; wp += 128L * 64 * sizeof(bf16);
    bf16* w2sh_l = (bf16*)wp; wp += 128L * 64 * sizeof(bf16);
    bf16* mlp1_h = (bf16*)wp; wp += 192L * 128 * sizeof(bf16);
    bf16* mlp1_l = (bf16*)wp; wp += 192L * 128 * sizeof(bf16);
    bf16* mlp2_h = (bf16*)wp; wp += 128L * 64 * sizeof(bf16);
    bf16* mlp2_l = (bf16*)wp; wp += 128L * 64 * sizeof(bf16);
    bf16* raw1_h = (bf16*)wp; wp += 256L * 64 * sizeof(bf16);
    bf16* raw1_l = (bf16*)wp; wp += 256L * 64 * sizeof(bf16);
    bf16* raw2_h = (bf16*)wp; wp += 64L * 64 * sizeof(bf16);
    bf16* raw2_l = (bf16*)wp; wp += 64L * 64 * sizeof(bf16);
    bf16* proj_h = (bf16*)wp; wp += 256L * 64 * sizeof(bf16);
    bf16* proj_l = (bf16*)wp; wp += 256L * 64 * sizeof(bf16);

    int* rowptr[NP]; int2* csr[NP];
    for (int p = 0; p < NP; ++p) {
        rowptr[p] = rowptr_all + (long)p * NNR;
        csr[p]    = csr_all + (long)p * NE;
    }

    const int TB = 256;
    int g_rows = cdiv(NN, 64);  // 782

    // ---- weight prep (transpose + hi/lo split) ----
    transpose_split<<<cdiv(3L * 256 * 128, TB), TB, 0, stream>>>(spec_w1, w1sp_h, w1sp_l, 256, 128, 3L * 256 * 128);
    transpose_split<<<cdiv(256L * 128, TB), TB, 0, stream>>>(shared_w1, w1sh_h, w1sh_l, 256, 128, 256L * 128);
    transpose_split<<<cdiv(3L * 128 * 64, TB), TB, 0, stream>>>(spec_w2, w2sp_h, w2sp_l, 128, 64, 3L * 128 * 64);
    transpose_split<<<cdiv(128L * 64, TB), TB, 0, stream>>>(shared_w2, w2sh_h, w2sh_l, 128, 64, 128L * 64);
    transpose_split<<<cdiv(192L * 128, TB), TB, 0, stream>>>(mlp_w1, mlp1_h, mlp1_l, 192, 128, 192L * 128);
    transpose_split<<<cdiv(128L * 64, TB), TB, 0, stream>>>(mlp_w2, mlp2_h, mlp2_l, 128, 64, 128L * 64);
    transpose_split<<<cdiv(256L * 64, TB), TB, 0, stream>>>(raw_w1, raw1_h, raw1_l, 256, 64, 256L * 64);
    transpose_split<<<cdiv(64L * 64, TB), TB, 0, stream>>>(raw_w2, raw2_h, raw2_l, 64, 64, 64L * 64);
    transpose_split<<<cdiv(256L * 64, TB), TB, 0, stream>>>(proj_w, proj_h, proj_l, 256, 64, 256L * 64);

    // ---- build CSR (bucket append -> bucket-local hist/scan/scatter) ----
    hipMemsetAsync(bcnt, 0, (long)NP * NBUK * sizeof(int), stream);
    {
        dim3 gA(cdiv(NE, EPB), NP);
        bucket_append2<<<gA, 256, 0, stream>>>(edge_index, edge_val, bcnt, bbuf);
        scan_bcnt<<<NP, NBUK, 0, stream>>>(bcnt, bbase);
        dim3 gB(NBUK, NP);
        bucket_scatter3<<<gB, 256, 0, stream>>>(bcnt, bbase, bbuf, rowptr_all, csr_all);
    }

    // ---- shared layer-1 GEMM (once) ----
    gemm_mfma<256, 128, 0, 0, bf16><<<g_rows, 256, 0, stream>>>(
        feature, w1sh_h, w1sh_l, nullptr, XWsh, NN, nullptr, nullptr, nullptr, nullptr);

    // ---- per plane: fused spec+shared pipeline ----
    for (int p = 0; p < NP; ++p) {
        gemm_mfma<256, 128, 0, 0, bf16><<<g_rows, 256, 0, stream>>>(
            feature, w1sp_h + (long)p * 256 * 128, w1sp_l + (long)p * 256 * 128,
            nullptr, XWsp, NN, nullptr, nullptr, nullptr, nullptr);
        spmm_dual<128, 1, 1><<<NN, 64, 0, stream>>>(rowptr[p], csr[p], XWsp, XWsh,
                                                    spec_b1 + (long)p * 128, shared_b1,
                                                    h1sp, h1sh);
        gemm_mfma<128, 64, 0, 0, bf16><<<g_rows, 256, 0, stream>>>(
            h1sp, w2sp_h + (long)p * 128 * 64, w2sp_l + (long)p * 128 * 64,
            nullptr, Bsp, NN, nullptr, nullptr, nullptr, nullptr);
        gemm_mfma<128, 64, 0, 0, bf16><<<g_rows, 256, 0, stream>>>(
            h1sh, w2sh_h, w2sh_l, nullptr, Bsh, NN, nullptr, nullptr, nullptr, nullptr);
        spmm_dual<64, 0, 2><<<cdiv(NN, 2), 64, 0, stream>>>(rowptr[p], csr[p], Bsp, Bsh,
                                                            spec_b2 + (long)p * 64, shared_b2,
                                                            spec_stack + (long)p * NN * OUTD,
                                                            shr_stack + (long)p * NN * OUTD);
    }

    // ---- summaries + random walk ----
    {
        dim3 gA(NCH, 3);
        colsum_passA<<<gA, 256, 0, stream>>>(spec_stack, pMax, pSum, pExp);
        colsum_reduceB<<<192, 64, 0, stream>>>(pMax, pSum, pExp, psBuf, zBuf);
        colsum_passC<<<gA, 256, 0, stream>>>(spec_stack, psBuf, zBuf, pEnt);
        colsum_reduceD<<<192, 64, 0, stream>>>(pEnt, psBuf);
    }
    walk_kernel<<<1, 64, 0, stream>>>(psBuf, weight_b, tau, wBuf);

    // ---- H_col (hidden reuses h1sp) ----
    gemm_mfma<192, 128, 1, 2, float><<<g_rows, 256, 0, stream>>>(
        spec_stack, mlp1_h, mlp1_l, mlp_b1, h1sp, NN, nullptr, nullptr, nullptr, nullptr);
    gemm_mfma<128, 64, 0, 0, float><<<g_rows, 256, 0, stream>>>(
        h1sp, mlp2_h, mlp2_l, mlp_b2, Hcol, NN, nullptr, nullptr, nullptr, nullptr);

    // ---- H_raw (U1 reuses h1sh; RB1/RB2 reuse Bsp/Bsh) ----
    float* U1 = h1sh;
    gemm_mfma<256, 64, 0, 0, bf16><<<g_rows, 256, 0, stream>>>(
        feature, raw1_h, raw1_l, nullptr, Bsp, NN, nullptr, nullptr, nullptr, nullptr);
    spmm_merged<<<cdiv(NN, 2), 64, 0, stream>>>(rowptr[0], csr[0],
                                                rowptr[1], csr[1],
                                                rowptr[2], csr[2],
                                                Bsp, wBuf, raw_b1, U1);
    gemm_mfma<64, 64, 0, 0, bf16><<<g_rows, 256, 0, stream>>>(
        U1, raw2_h, raw2_l, nullptr, Bsh, NN, nullptr, nullptr, nullptr, nullptr);
    spmm_merged<<<cdiv(NN, 2), 64, 0, stream>>>(rowptr[0], csr[0],
                                                rowptr[1], csr[1],
                                                rowptr[2], csr[2],
                                                Bsh, wBuf, raw_b2, Hraw);
    hraw_final<<<cdiv((long)NN * OUTD, TB), TB, 0, stream>>>(U1, Hraw);

    // ---- final projection (mix fused into A-loader) ----
    gemm_mfma<256, 64, 2, 0, float><<<g_rows, 256, 0, stream>>>(
        spec_stack, proj_h, proj_l, proj_b, out, NN, wBuf, shr_stack, Hcol, Hraw);
}

// Round 9
// 1310.047 us; speedup vs baseline: 1.8059x; 1.0743x over previous
//
#include <hip/hip_runtime.h>
#include <hip/hip_bf16.h>
#include <math.h>

#define NN 50000
#define NFEAT 256
#define NHID 128
#define OUTD 64
#define NE 800000
#define NP 3
#define NCH 500  // col-summary chunks: 500*100 = 50000 exactly (no empty chunks!)
#define RC 100   // rows per chunk
#define NNR (NN + 1)  // rowptr stride per plane
#define NBUK 256
#define BROWS 196   // ceil(NN/NBUK)
#define BCAP 4096   // mean bucket = 3136, +17 sigma
#define EPB 8192    // edges per append block

typedef __hip_bfloat16 bf16;
typedef __attribute__((ext_vector_type(8))) short short8;
typedef __attribute__((ext_vector_type(4))) short short4v;
typedef __attribute__((ext_vector_type(4))) float f32x4;
typedef unsigned long long u64;

static inline int cdiv(long a, long b) { return (int)((a + b - 1) / b); }

// RNE f32 -> bf16 bits (finite inputs only)
__device__ __forceinline__ short f2bf(float x) {
    unsigned u = __builtin_bit_cast(unsigned, x);
    unsigned r = (u + 0x7FFFu + ((u >> 16) & 1u)) >> 16;
    return (short)r;
}
__device__ __forceinline__ float bf2f(short b) {
    unsigned u = ((unsigned)(unsigned short)b) << 16;
    return __builtin_bit_cast(float, u);
}

__device__ __forceinline__ float telu_f(float x) {
    float e = __expf(x);
    float t = __expf(-2.0f * e);
    return x * (1.0f - t) / (1.0f + t);
}

__device__ __forceinline__ void ld8(const float* __restrict__ p, float v[8]) {
    float4 a = *reinterpret_cast<const float4*>(p);
    float4 b = *reinterpret_cast<const float4*>(p + 4);
    v[0] = a.x; v[1] = a.y; v[2] = a.z; v[3] = a.w;
    v[4] = b.x; v[5] = b.y; v[6] = b.z; v[7] = b.w;
}

__device__ __forceinline__ void store4(float* p, const float o[4]) {
    *reinterpret_cast<float4*>(p) = make_float4(o[0], o[1], o[2], o[3]);
}
__device__ __forceinline__ void store4(bf16* p, const float o[4]) {
    short4v u;
    u[0] = f2bf(o[0]); u[1] = f2bf(o[1]); u[2] = f2bf(o[2]); u[3] = f2bf(o[3]);
    *reinterpret_cast<short4v*>(p) = u;
}

// =============== weight prep: transpose + hi/lo bf16 split ===============
// src: (P,K,M) f32 row-major -> dh/dl: (P,M,K) bf16
__global__ void transpose_split(const float* __restrict__ src, bf16* __restrict__ dh,
                                bf16* __restrict__ dl, int K, int M, long total) {
    long idx = (long)blockIdx.x * blockDim.x + threadIdx.x;
    if (idx >= total) return;
    long pm = idx / K;
    int k = (int)(idx - pm * K);
    long p = pm / M;
    int m = (int)(pm - p * M);
    float v = src[(p * K + k) * M + m];
    short hb = f2bf(v);
    short lb = f2bf(v - bf2f(hb));
    reinterpret_cast<short*>(dh)[idx] = hb;
    reinterpret_cast<short*>(dl)[idx] = lb;
}

// =============== MFMA GEMM ===============
// out[n, m] = sum_k A[n,k] * B[k,m]  (B pre-transposed/split: Bh/Bl are [m][k] bf16)
// BM=64 rows/block, 4 waves x 16 rows, BK=32. hi/lo split on BOTH operands
// (3 MFMAs: ah*bh + ah*bl + al*bh) => f32-equivalent accuracy.
// MODE: 0 plain A[n*K+k]; 1 concat3 planes (spec_stack, K=192); 2 final mix (K=256)
// ACT: 0 none, 2 relu. OT: float or bf16.
template <int K, int M, int MODE, int ACT, typename OT>
__global__ __launch_bounds__(256) void gemm_mfma(
    const float* __restrict__ A, const bf16* __restrict__ Bh, const bf16* __restrict__ Bl,
    const float* __restrict__ bias, OT* __restrict__ out, int nrows,
    const float* __restrict__ wvec, const float* __restrict__ s1,
    const float* __restrict__ s2, const float* __restrict__ s3) {
    constexpr int MC = M / 16;
    __shared__ short AsH[64 * 32];
    __shared__ short AsL[64 * 32];

    int t = threadIdx.x;
    int n0 = blockIdx.x * 64;
    int w = t >> 6;
    int l = t & 63;
    int lr = l & 15, lq = l >> 4;

    float w0 = 0.f, w1 = 0.f, w2 = 0.f;
    if (MODE == 2) { w0 = wvec[3]; w1 = wvec[4]; w2 = wvec[5]; }

    f32x4 acc[MC];
#pragma unroll
    for (int i = 0; i < MC; ++i) {
        f32x4 z = {0.f, 0.f, 0.f, 0.f};
        acc[i] = z;
    }

    // staging coords: 256 threads cover 64 rows x 32 k; row = t>>2, 8-elem chunk = t&3
    int sr = t >> 2, sc = t & 3;
    int gn_s = n0 + sr;
    int wslot = (sc ^ ((sr >> 2) & 3)) << 3;   // XOR-swizzled 16B slot
    short* wpH = &AsH[sr * 32 + wslot];
    short* wpL = &AsL[sr * 32 + wslot];

    // fragment-read coords: wave w owns rows [w*16, w*16+16)
    int rrow = (w << 4) + lr;
    int roff = rrow * 32 + ((lq ^ ((rrow >> 2) & 3)) << 3);
    const short* rpH = &AsH[roff];
    const short* rpL = &AsL[roff];

    const short* Bhs = reinterpret_cast<const short*>(Bh);
    const short* Bls = reinterpret_cast<const short*>(Bl);

    auto loadA = [&](int k0, float v[8]) {
        if (gn_s >= nrows) {
#pragma unroll
            for (int j = 0; j < 8; ++j) v[j] = 0.f;
            return;
        }
        if (MODE == 0) {
            ld8(A + (long)gn_s * K + k0 + sc * 8, v);
        } else if (MODE == 1) {
            int plane = k0 >> 6;
            int d = (k0 & 63) + sc * 8;
            ld8(A + ((long)plane * NN + gn_s) * OUTD + d, v);
        } else {
            int seg = k0 >> 6;
            int d = (k0 & 63) + sc * 8;
            if (seg == 0) {
                float x0[8], x1[8], x2[8];
                ld8(A + ((long)0 * NN + gn_s) * OUTD + d, x0);
                ld8(A + ((long)1 * NN + gn_s) * OUTD + d, x1);
                ld8(A + ((long)2 * NN + gn_s) * OUTD + d, x2);
#pragma unroll
                for (int j = 0; j < 8; ++j) v[j] = w0 * x0[j] + w1 * x1[j] + w2 * x2[j];
            } else if (seg == 1) {
                float x0[8], x1[8], x2[8];
                ld8(s1 + ((long)0 * NN + gn_s) * OUTD + d, x0);
                ld8(s1 + ((long)1 * NN + gn_s) * OUTD + d, x1);
                ld8(s1 + ((long)2 * NN + gn_s) * OUTD + d, x2);
#pragma unroll
                for (int j = 0; j < 8; ++j) v[j] = (x0[j] + x1[j] + x2[j]) * (1.0f / 3.0f);
            } else if (seg == 2) {
                ld8(s2 + (long)gn_s * OUTD + d, v);
            } else {
                ld8(s3 + (long)gn_s * OUTD + d, v);
            }
        }
    };

    float v[8];
    loadA(0, v);
    for (int k0 = 0; k0 < K; k0 += 32) {
        short8 ah, al;
#pragma unroll
        for (int j = 0; j < 8; ++j) {
            short hb = f2bf(v[j]);
            ah[j] = hb;
            al[j] = f2bf(v[j] - bf2f(hb));
        }
        __syncthreads();  // previous iter's fragment reads done
        *reinterpret_cast<short8*>(wpH) = ah;
        *reinterpret_cast<short8*>(wpL) = al;
        __syncthreads();
        if (k0 + 32 < K) loadA(k0 + 32, v);  // prefetch next tile while MFMAs run
        short8 fah = *reinterpret_cast<const short8*>(rpH);
        short8 fal = *reinterpret_cast<const short8*>(rpL);
#pragma unroll
        for (int m = 0; m < MC; ++m) {
            long wb = (long)(m * 16 + lr) * K + k0 + (lq << 3);
            short8 bh = *reinterpret_cast<const short8*>(Bhs + wb);
            short8 bl = *reinterpret_cast<const short8*>(Bls + wb);
            // D layout (verified): m = (lane>>4)*4+reg, n = lane&15
            acc[m] = __builtin_amdgcn_mfma_f32_16x16x32_bf16(bh, fah, acc[m], 0, 0, 0);
            acc[m] = __builtin_amdgcn_mfma_f32_16x16x32_bf16(bl, fah, acc[m], 0, 0, 0);
            acc[m] = __builtin_amdgcn_mfma_f32_16x16x32_bf16(bh, fal, acc[m], 0, 0, 0);
        }
    }

    int gn = n0 + (w << 4) + lr;
    if (gn < nrows) {
#pragma unroll
        for (int m = 0; m < MC; ++m) {
            int mb = m * 16 + (lq << 2);
            float o[4];
#pragma unroll
            for (int r = 0; r < 4; ++r) {
                o[r] = acc[m][r] + (bias ? bias[mb + r] : 0.f);
                if (ACT == 2) o[r] = fmaxf(o[r], 0.f);
            }
            store4(&out[(long)gn * M + mb], o);
        }
    }
}

// =============== CSR build (bucket append + bucket-local hist/scan/scatter) ===============
// pass 1: LDS-aggregated bucket append. Each block owns EPB edges:
// LDS histogram -> ONE global atomicAdd per (block,bucket) (75K total) ->
// write packed {row_off<<16|col, val} at bucket tails (line-friendly runs).
__global__ __launch_bounds__(256) void bucket_append2(
    const int* __restrict__ ei, const float* __restrict__ ev,
    int* __restrict__ bcnt, int2* __restrict__ bbuf) {
    int p = blockIdx.y;
    int t = threadIdx.x;
    long e0 = (long)blockIdx.x * EPB;
    const int* rs = ei + ((long)p * 2) * NE;
    const int* cs = rs + NE;
    const float* vs = ev + (long)p * NE;
    __shared__ int lcnt[NBUK];
    __shared__ int lbase[NBUK];
    for (int b = t; b < NBUK; b += 256) lcnt[b] = 0;
    __syncthreads();
    for (int i = t; i < EPB; i += 256) {
        long e = e0 + i;
        if (e < NE) atomicAdd(&lcnt[rs[e] / BROWS], 1);
    }
    __syncthreads();
    for (int b = t; b < NBUK; b += 256) {
        int c = lcnt[b];
        lbase[b] = (c > 0) ? atomicAdd(&bcnt[p * NBUK + b], c) : 0;
        lcnt[b] = 0;
    }
    __syncthreads();
    for (int i = t; i < EPB; i += 256) {
        long e = e0 + i;
        if (e >= NE) continue;
        int r = rs[e];
        int b = r / BROWS;
        int off = atomicAdd(&lcnt[b], 1);
        int pos = lbase[b] + off;
        int meta = ((r - b * BROWS) << 16) | cs[e];  // col < 50000 < 2^16
        bbuf[((long)p * NBUK + b) * BCAP + pos] = make_int2(meta, __float_as_int(vs[e]));
    }
}

// exclusive scan of per-bucket totals -> global bucket base offsets (one block/plane)
__global__ void scan_bcnt(const int* __restrict__ bcnt, int* __restrict__ bbase) {
    int p = blockIdx.x, t = threadIdx.x;
    int v = bcnt[p * NBUK + t];
    __shared__ int sh[NBUK];
    sh[t] = v;
    __syncthreads();
    for (int off = 1; off < NBUK; off <<= 1) {
        int tmp = (t >= off) ? sh[t - off] : 0;
        __syncthreads();
        sh[t] += tmp;
        __syncthreads();
    }
    bbase[p * NBUK + t] = sh[t] - v;  // exclusive
}

// pass 2: one workgroup per (bucket, plane). Derives rowptr for its row range
// from an LDS histogram of its own bbuf entries (no device-scope atomics),
// then scatters; CSR writes confined to a ~25KB span from ONE CU.
__global__ __launch_bounds__(256) void bucket_scatter3(
    const int* __restrict__ bcnt, const int* __restrict__ bbase,
    const int2* __restrict__ bbuf, int* __restrict__ rowptr, int2* __restrict__ csr) {
    int b = blockIdx.x, p = blockIdx.y;
    int t = threadIdx.x;
    int row0 = b * BROWS;
    int nrows = min(BROWS, NN - row0);
    int cntb = bcnt[p * NBUK + b];
    int base = bbase[p * NBUK + b];
    const int2* buf = bbuf + ((long)p * NBUK + b) * BCAP;
    __shared__ int rcnt[256];
    __shared__ int cur[BROWS];
    rcnt[t] = 0;
    __syncthreads();
    // LDS row histogram of this bucket's edges (coalesced reads)
    for (int i = t; i < cntb; i += 256) atomicAdd(&rcnt[buf[i].x >> 16], 1);
    __syncthreads();
    // exclusive scan over the 196 row counters (padded to 256)
    int v = rcnt[t];
    __shared__ int sh[256];
    sh[t] = v;
    __syncthreads();
    for (int off = 1; off < 256; off <<= 1) {
        int tmp = (t >= off) ? sh[t - off] : 0;
        __syncthreads();
        sh[t] += tmp;
        __syncthreads();
    }
    int excl = base + sh[t] - v;
    if (t < nrows) {
        rowptr[(long)p * NNR + row0 + t] = excl;
        cur[t] = excl;
    }
    if (b == NBUK - 1 && t == 0) rowptr[(long)p * NNR + NN] = base + cntb;
    __syncthreads();
    // scatter
    int2* csrp = csr + (long)p * NE;
    for (int i = t; i < cntb; i += 256) {
        int2 ent = buf[i];
        int row_off = ent.x >> 16;
        int col = ent.x & 0xFFFF;
        int pos = atomicAdd(&cur[row_off], 1);
        csrp[pos] = make_int2(col, ent.y);
    }
}

// =============== fused dual gather SpMM (bf16x2 gathers, packed csr) ===============
// RPB rows per block, M/2 threads per row. ACT: 0 none, 1 telu.
template <int M, int ACT, int RPB>
__global__ void spmm_dual(const int* __restrict__ rowptr, const int2* __restrict__ csr,
                          const bf16* __restrict__ Ya, const bf16* __restrict__ Yb,
                          const float* __restrict__ biasA, const float* __restrict__ biasB,
                          float* __restrict__ outA, float* __restrict__ outB) {
    constexpr int TPR = M / 2;
    int t = threadIdx.x;
    int n = blockIdx.x * RPB + t / TPR;
    int hs = t % TPR;          // bf16x2 slot
    int h = hs * 2;            // column
    if (n >= NN) return;
    int e0 = rowptr[n], e1 = rowptr[n + 1];
    float aAl = biasA[h], aAh = biasA[h + 1];
    float aBl = biasB[h], aBh = biasB[h + 1];
    const unsigned* Ua = reinterpret_cast<const unsigned*>(Ya);
    const unsigned* Ub = reinterpret_cast<const unsigned*>(Yb);
    int e = e0;
    for (; e + 3 < e1; e += 4) {
        int2 p0 = csr[e], p1 = csr[e + 1], p2 = csr[e + 2], p3 = csr[e + 3];
        unsigned a0 = Ua[(long)p0.x * TPR + hs], a1 = Ua[(long)p1.x * TPR + hs];
        unsigned a2 = Ua[(long)p2.x * TPR + hs], a3 = Ua[(long)p3.x * TPR + hs];
        unsigned b0 = Ub[(long)p0.x * TPR + hs], b1 = Ub[(long)p1.x * TPR + hs];
        unsigned b2 = Ub[(long)p2.x * TPR + hs], b3 = Ub[(long)p3.x * TPR + hs];
        float v0 = __int_as_float(p0.y), v1 = __int_as_float(p1.y);
        float v2 = __int_as_float(p2.y), v3 = __int_as_float(p3.y);
        aAl += v0 * bf2f((short)a0) + v1 * bf2f((short)a1) + v2 * bf2f((short)a2) + v3 * bf2f((short)a3);
        aAh += v0 * bf2f((short)(a0 >> 16)) + v1 * bf2f((short)(a1 >> 16)) +
               v2 * bf2f((short)(a2 >> 16)) + v3 * bf2f((short)(a3 >> 16));
        aBl += v0 * bf2f((short)b0) + v1 * bf2f((short)b1) + v2 * bf2f((short)b2) + v3 * bf2f((short)b3);
        aBh += v0 * bf2f((short)(b0 >> 16)) + v1 * bf2f((short)(b1 >> 16)) +
               v2 * bf2f((short)(b2 >> 16)) + v3 * bf2f((short)(b3 >> 16));
    }
    for (; e < e1; ++e) {
        int2 pe = csr[e];
        float v = __int_as_float(pe.y);
        unsigned a = Ua[(long)pe.x * TPR + hs];
        unsigned b = Ub[(long)pe.x * TPR + hs];
        aAl += v * bf2f((short)a);
        aAh += v * bf2f((short)(a >> 16));
        aBl += v * bf2f((short)b);
        aBh += v * bf2f((short)(b >> 16));
    }
    if (ACT == 1) {
        aAl = telu_f(aAl); aAh = telu_f(aAh);
        aBl = telu_f(aBl); aBh = telu_f(aBh);
    }
    *reinterpret_cast<float2*>(&outA[(long)n * M + h]) = make_float2(aAl, aAh);
    *reinterpret_cast<float2*>(&outB[(long)n * M + h]) = make_float2(aBl, aBh);
}

// merged 3-plane spmm (bf16x2 gathers); RPB rows per 256-thread block
__global__ void spmm_merged(const int* __restrict__ rp0, const int2* __restrict__ cs0,
                            const int* __restrict__ rp1, const int2* __restrict__ cs1,
                            const int* __restrict__ rp2, const int2* __restrict__ cs2,
                            const bf16* __restrict__ Y, const float* __restrict__ wvec,
                            const float* __restrict__ bias, float* __restrict__ out) {
    constexpr int TPR = 32;
    constexpr int RPB = 8;
    int t = threadIdx.x;
    int n = blockIdx.x * RPB + t / TPR;
    int hs = t % TPR;
    int h = hs * 2;
    if (n >= NN) return;
    const int* rps[3] = {rp0, rp1, rp2};
    const int2* css[3] = {cs0, cs1, cs2};
    const unsigned* U = reinterpret_cast<const unsigned*>(Y);
    float al = 0.f, ah = 0.f;
#pragma unroll
    for (int p = 0; p < 3; ++p) {
        const int2* cs = css[p];
        int e0 = rps[p][n], e1 = rps[p][n + 1];
        float sl = 0.f, sh = 0.f;
        int e = e0;
        for (; e + 3 < e1; e += 4) {
            int2 p0 = cs[e], p1 = cs[e + 1], p2 = cs[e + 2], p3 = cs[e + 3];
            unsigned y0 = U[(long)p0.x * TPR + hs], y1 = U[(long)p1.x * TPR + hs];
            unsigned y2 = U[(long)p2.x * TPR + hs], y3 = U[(long)p3.x * TPR + hs];
            float v0 = __int_as_float(p0.y), v1 = __int_as_float(p1.y);
            float v2 = __int_as_float(p2.y), v3 = __int_as_float(p3.y);
            sl += v0 * bf2f((short)y0) + v1 * bf2f((short)y1) + v2 * bf2f((short)y2) + v3 * bf2f((short)y3);
            sh += v0 * bf2f((short)(y0 >> 16)) + v1 * bf2f((short)(y1 >> 16)) +
                  v2 * bf2f((short)(y2 >> 16)) + v3 * bf2f((short)(y3 >> 16));
        }
        for (; e < e1; ++e) {
            int2 pe = cs[e];
            unsigned y = U[(long)pe.x * TPR + hs];
            float v = __int_as_float(pe.y);
            sl += v * bf2f((short)y);
            sh += v * bf2f((short)(y >> 16));
        }
        float wv = wvec[p];
        al += wv * sl;
        ah += wv * sh;
    }
    *reinterpret_cast<float2*>(&out[(long)n * OUTD + h]) =
        make_float2(al + bias[h], ah + bias[h + 1]);
}

// =============== column summaries (coalesced, chunked, NCH=500) ===============
__global__ void colsum_passA(const float* __restrict__ spec, float* __restrict__ pmax,
                             float* __restrict__ psum, float* __restrict__ pexp) {
    int p = blockIdx.y, c = blockIdx.x;
    int t = threadIdx.x;
    int d = t & 63, rg = t >> 6;
    const float* base = spec + (long)p * NN * OUTD;
    int r0 = c * RC, r1 = min(r0 + RC, NN);
    float m = -INFINITY, s = 0.f, e = 0.f;
    for (int r = r0 + rg; r < r1; r += 4) {
        float v = base[(long)r * OUTD + d];
        s += v;
        if (v > m) { e = e * __expf(m - v) + 1.0f; m = v; }
        else e += __expf(v - m);
    }
    __shared__ float rm[256], rs[256], re[256];
    rm[t] = m; rs[t] = s; re[t] = e;
    __syncthreads();
    for (int off = 128; off >= 64; off >>= 1) {
        if (t < off) {
            float m2 = fmaxf(rm[t], rm[t + off]);
            re[t] = re[t] * __expf(rm[t] - m2) + re[t + off] * __expf(rm[t + off] - m2);
            rm[t] = m2;
            rs[t] = rs[t] + rs[t + off];
        }
        __syncthreads();
    }
    if (t < 64) {
        long idx = ((long)p * 64 + t) * NCH + c;
        pmax[idx] = rm[t]; psum[idx] = rs[t]; pexp[idx] = re[t];
    }
}

// combine NCH chunk triples per (p,d); 256 threads, chunk-loop + LDS tree
__global__ void colsum_reduceB(const float* __restrict__ pmax, const float* __restrict__ psum,
                               const float* __restrict__ pexp, float* __restrict__ ps,
                               float* __restrict__ zbuf) {
    int b = blockIdx.x;  // p*64+d
    int p = b >> 6, d = b & 63;
    int t = threadIdx.x;
    float m = -INFINITY, s = 0.f, e = 0.f;
    for (int c = t; c < NCH; c += 256) {
        long idx = (long)b * NCH + c;
        float mm = pmax[idx], ss = psum[idx], ee = pexp[idx];
        float m2 = fmaxf(m, mm);
        e = e * __expf(m - m2) + ee * __expf(mm - m2);
        m = m2;
        s += ss;
    }
    __shared__ float rm[256], rs[256], re[256];
    rm[t] = m; rs[t] = s; re[t] = e;
    __syncthreads();
    for (int off = 128; off > 0; off >>= 1) {
        if (t < off) {
            float m2 = fmaxf(rm[t], rm[t + off]);
            re[t] = re[t] * __expf(rm[t] - m2) + re[t + off] * __expf(rm[t + off] - m2);
            rm[t] = m2;
            rs[t] = rs[t] + rs[t + off];
        }
        __syncthreads();
    }
    if (t == 0) {
        ps[p * 192 + d] = rs[0] / (float)NN;
        ps[p * 192 + 64 + d] = rm[0];
        zbuf[b] = re[0];
    }
}

__global__ void colsum_passC(const float* __restrict__ spec, const float* __restrict__ ps,
                             const float* __restrict__ zbuf, float* __restrict__ pent) {
    int p = blockIdx.y, c = blockIdx.x;
    int t = threadIdx.x;
    int d = t & 63, rg = t >> 6;
    const float* base = spec + (long)p * NN * OUTD;
    float gm = ps[p * 192 + 64 + d];
    float zinv = 1.0f / zbuf[p * 64 + d];
    int r0 = c * RC, r1 = min(r0 + RC, NN);
    float ent = 0.f;
    for (int r = r0 + rg; r < r1; r += 4) {
        float v = base[(long)r * OUTD + d];
        float pv = __expf(v - gm) * zinv;
        ent -= pv * __logf(pv + 1e-6f);
    }
    __shared__ float rd[256];
    rd[t] = ent;
    __syncthreads();
    for (int off = 128; off >= 64; off >>= 1) {
        if (t < off) rd[t] += rd[t + off];
        __syncthreads();
    }
    if (t < 64) pent[((long)p * 64 + t) * NCH + c] = rd[t];
}

__global__ void colsum_reduceD(const float* __restrict__ pent, float* __restrict__ ps) {
    int b = blockIdx.x;
    int p = b >> 6, d = b & 63;
    int t = threadIdx.x;
    float e = 0.f;
    for (int c = t; c < NCH; c += 256) e += pent[(long)b * NCH + c];
    __shared__ float rd[256];
    rd[t] = e;
    __syncthreads();
    for (int off = 128; off > 0; off >>= 1) {
        if (t < off) rd[t] += rd[t + off];
        __syncthreads();
    }
    if (t == 0) ps[p * 192 + 128 + d] = rd[0];
}

// =============== walk + epilogue ===============
__global__ void walk_kernel(const float* __restrict__ ps, const float* __restrict__ weight_b,
                            const float* __restrict__ tau_p, float* __restrict__ wout) {
    if (threadIdx.x != 0 || blockIdx.x != 0) return;
    float sim[3][3];
    float inv = 1.0f / (sqrtf(192.0f) * tau_p[0]);
    for (int i = 0; i < 3; ++i)
        for (int j = 0; j < 3; ++j) {
            float dotv = 0.f;
            for (int k = 0; k < 192; ++k) dotv += ps[i * 192 + k] * ps[j * 192 + k];
            sim[i][j] = dotv * inv;
        }
    float T[3][3];
    for (int i = 0; i < 3; ++i) {
        float m = fmaxf(sim[i][0], fmaxf(sim[i][1], sim[i][2]));
        float e0 = expf(sim[i][0] - m), e1 = expf(sim[i][1] - m), e2 = expf(sim[i][2] - m);
        float s = e0 + e1 + e2;
        T[i][0] = e0 / s; T[i][1] = e1 / s; T[i][2] = e2 / s;
    }
    float b0 = weight_b[0], b1 = weight_b[1], b2 = weight_b[2];
    float m = fmaxf(b0, fmaxf(b1, b2));
    float e0 = expf(b0 - m), e1 = expf(b1 - m), e2 = expf(b2 - m);
    float s = e0 + e1 + e2;
    float pi0[3] = {e0 / s, e1 / s, e2 / s};
    float pi[3] = {pi0[0], pi0[1], pi0[2]};
    for (int it = 0; it < 13; ++it) {
        float n0 = pi[0] * T[0][0] + pi[1] * T[1][0] + pi[2] * T[2][0];
        float n1 = pi[0] * T[0][1] + pi[1] * T[1][1] + pi[2] * T[2][1];
        float n2 = pi[0] * T[0][2] + pi[1] * T[1][2] + pi[2] * T[2][2];
        pi[0] = 0.2f * pi0[0] + 0.8f * n0;
        pi[1] = 0.2f * pi0[1] + 0.8f * n1;
        pi[2] = 0.2f * pi0[2] + 0.8f * n2;
    }
    wout[0] = pi[0]; wout[1] = pi[1]; wout[2] = pi[2];
    float mm = fmaxf(pi[0], fmaxf(pi[1], pi[2]));
    float f0 = expf(pi[0] - mm), f1 = expf(pi[1] - mm), f2 = expf(pi[2] - mm);
    float fs = f0 + f1 + f2;
    wout[3] = f0 / fs; wout[4] = f1 / fs; wout[5] = f2 / fs;
}

__global__ void hraw_final(const float* __restrict__ U1, float* __restrict__ Hraw) {
    long i = (long)blockIdx.x * blockDim.x + threadIdx.x;
    if (i >= (long)NN * OUTD) return;
    Hraw[i] = 0.5f * (U1[i] + Hraw[i]);
}

extern "C" void kernel_launch(void* const* d_in, const int* in_sizes, int n_in,
                              void* d_out, int out_size, void* d_ws, size_t ws_size,
                              hipStream_t stream) {
    const float* feature   = (const float*)d_in[0];
    const int*   edge_index= (const int*)d_in[1];
    const float* edge_val  = (const float*)d_in[2];
    const float* spec_w1   = (const float*)d_in[3];
    const float* spec_b1   = (const float*)d_in[4];
    const float* spec_w2   = (const float*)d_in[5];
    const float* spec_b2   = (const float*)d_in[6];
    const float* shared_w1 = (const float*)d_in[7];
    const float* shared_b1 = (const float*)d_in[8];
    const float* shared_w2 = (const float*)d_in[9];
    const float* shared_b2 = (const float*)d_in[10];
    const float* weight_b  = (const float*)d_in[11];
    const float* tau       = (const float*)d_in[12];
    const float* mlp_w1    = (const float*)d_in[13];
    const float* mlp_b1    = (const float*)d_in[14];
    const float* mlp_w2    = (const float*)d_in[15];
    const float* mlp_b2    = (const float*)d_in[16];
    const float* raw_w1    = (const float*)d_in[17];
    const float* raw_b1    = (const float*)d_in[18];
    const float* raw_w2    = (const float*)d_in[19];
    const float* raw_b2    = (const float*)d_in[20];
    const float* proj_w    = (const float*)d_in[21];
    const float* proj_b    = (const float*)d_in[22];

    float* out        = (float*)d_out;
    float* spec_stack = out + (long)NN * OUTD;
    float* shr_stack  = spec_stack + 3L * NN * OUTD;
    float* Hcol       = out + 7L * NN * OUTD;
    float* Hraw       = out + 8L * NN * OUTD;

    // ---- workspace carve ----
    char* wp = (char*)d_ws;
    bf16* XWsp = (bf16*)wp; wp += (long)NN * 128 * sizeof(bf16);
    bf16* XWsh = (bf16*)wp; wp += (long)NN * 128 * sizeof(bf16);
    bf16* Bsp  = (bf16*)wp; wp += (long)NN * OUTD * sizeof(bf16);
    bf16* Bsh  = (bf16*)wp; wp += (long)NN * OUTD * sizeof(bf16);
    float* h1sp = (float*)wp; wp += (long)NN * 128 * sizeof(float);
    float* h1sh = (float*)wp; wp += (long)NN * 128 * sizeof(float);
    float* psBuf = (float*)wp; wp += 1024 * sizeof(float);
    float* wBuf  = (float*)wp; wp += 64 * sizeof(float);
    float* zBuf  = (float*)wp; wp += 256 * sizeof(float);
    float* pMax  = (float*)wp; wp += (long)3 * 64 * NCH * sizeof(float);
    float* pSum  = (float*)wp; wp += (long)3 * 64 * NCH * sizeof(float);
    float* pExp  = (float*)wp; wp += (long)3 * 64 * NCH * sizeof(float);
    float* pEnt  = (float*)wp; wp += (long)3 * 64 * NCH * sizeof(float);
    int2* csr_all = (int2*)wp;  wp += (long)NP * NE * sizeof(int2);
    int*  rowptr_all = (int*)wp; wp += (long)NP * NNR * sizeof(int) + 64;
    int* bcnt   = (int*)wp; wp += (long)NP * NBUK * sizeof(int);
    int* bbase  = (int*)wp; wp += (long)NP * NBUK * sizeof(int);
    int2* bbuf  = (int2*)wp; wp += (long)NP * NBUK * BCAP * sizeof(int2);
    // pre-split transposed weights (bf16 hi/lo, [m][k] layout)
    bf16* w1sp_h = (bf16*)wp; wp += 3L * 256 * 128 * sizeof(bf16);
    bf16* w1sp_l = (bf16*)wp; wp += 3L * 256 * 128 * sizeof(bf16);
    bf16* w1sh_h = (bf16*)wp; wp += 256L * 128 * sizeof(bf16);
    bf16* w1sh_l = (bf16*)wp; wp += 256L * 128 * sizeof(bf16);
    bf16* w2sp_h = (bf16*)wp; wp += 3L * 128 * 64 * sizeof(bf16);
    bf16* w2sp_l = (bf16*)wp; wp += 3L * 128 * 64 * sizeof(bf16);
    bf16* w2sh_h = (bf16*)wp; wp += 128L * 64 * sizeof(bf16);
    bf16* w2sh_l = (bf16*)wp; wp += 128L * 64 * sizeof(bf16);
    bf16* mlp1_h = (bf16*)wp; wp += 192L * 128 * sizeof(bf16);
    bf16* mlp1_l = (bf16*)wp; wp += 192L * 128 * sizeof(bf16);
    bf16* mlp2_h = (bf16*)wp; wp += 128L * 64 * sizeof(bf16);
    bf16* mlp2_l = (bf16*)wp; wp += 128L * 64 * sizeof(bf16);
    bf16* raw1_h = (bf16*)wp; wp += 256L * 64 * sizeof(bf16);
    bf16* raw1_l = (bf16*)wp; wp += 256L * 64 * sizeof(bf16);
    bf16* raw2_h = (bf16*)wp; wp += 64L * 64 * sizeof(bf16);
    bf16* raw2_l = (bf16*)wp; wp += 64L * 64 * sizeof(bf16);
    bf16* proj_h = (bf16*)wp; wp += 256L * 64 * sizeof(bf16);
    bf16* proj_l = (bf16*)wp; wp += 256L * 64 * sizeof(bf16);

    int* rowptr[NP]; int2* csr[NP];
    for (int p = 0; p < NP; ++p) {
        rowptr[p] = rowptr_all + (long)p * NNR;
        csr[p]    = csr_all + (long)p * NE;
    }

    const int TB = 256;
    int g_rows = cdiv(NN, 64);  // 782

    // ---- weight prep (transpose + hi/lo split) ----
    transpose_split<<<cdiv(3L * 256 * 128, TB), TB, 0, stream>>>(spec_w1, w1sp_h, w1sp_l, 256, 128, 3L * 256 * 128);
    transpose_split<<<cdiv(256L * 128, TB), TB, 0, stream>>>(shared_w1, w1sh_h, w1sh_l, 256, 128, 256L * 128);
    transpose_split<<<cdiv(3L * 128 * 64, TB), TB, 0, stream>>>(spec_w2, w2sp_h, w2sp_l, 128, 64, 3L * 128 * 64);
    transpose_split<<<cdiv(128L * 64, TB), TB, 0, stream>>>(shared_w2, w2sh_h, w2sh_l, 128, 64, 128L * 64);
    transpose_split<<<cdiv(192L * 128, TB), TB, 0, stream>>>(mlp_w1, mlp1_h, mlp1_l, 192, 128, 192L * 128);
    transpose_split<<<cdiv(128L * 64, TB), TB, 0, stream>>>(mlp_w2, mlp2_h, mlp2_l, 128, 64, 128L * 64);
    transpose_split<<<cdiv(256L * 64, TB), TB, 0, stream>>>(raw_w1, raw1_h, raw1_l, 256, 64, 256L * 64);
    transpose_split<<<cdiv(64L * 64, TB), TB, 0, stream>>>(raw_w2, raw2_h, raw2_l, 64, 64, 64L * 64);
    transpose_split<<<cdiv(256L * 64, TB), TB, 0, stream>>>(proj_w, proj_h, proj_l, 256, 64, 256L * 64);

    // ---- build CSR (bucket append -> bucket-local hist/scan/scatter) ----
    hipMemsetAsync(bcnt, 0, (long)NP * NBUK * sizeof(int), stream);
    {
        dim3 gA(cdiv(NE, EPB), NP);
        bucket_append2<<<gA, 256, 0, stream>>>(edge_index, edge_val, bcnt, bbuf);
        scan_bcnt<<<NP, NBUK, 0, stream>>>(bcnt, bbase);
        dim3 gB(NBUK, NP);
        bucket_scatter3<<<gB, 256, 0, stream>>>(bcnt, bbase, bbuf, rowptr_all, csr_all);
    }

    // ---- shared layer-1 GEMM (once) ----
    gemm_mfma<256, 128, 0, 0, bf16><<<g_rows, 256, 0, stream>>>(
        feature, w1sh_h, w1sh_l, nullptr, XWsh, NN, nullptr, nullptr, nullptr, nullptr);

    // ---- per plane: fused spec+shared pipeline ----
    for (int p = 0; p < NP; ++p) {
        gemm_mfma<256, 128, 0, 0, bf16><<<g_rows, 256, 0, stream>>>(
            feature, w1sp_h + (long)p * 256 * 128, w1sp_l + (long)p * 256 * 128,
            nullptr, XWsp, NN, nullptr, nullptr, nullptr, nullptr);
        spmm_dual<128, 1, 4><<<cdiv(NN, 4), 256, 0, stream>>>(rowptr[p], csr[p], XWsp, XWsh,
                                                              spec_b1 + (long)p * 128, shared_b1,
                                                              h1sp, h1sh);
        gemm_mfma<128, 64, 0, 0, bf16><<<g_rows, 256, 0, stream>>>(
            h1sp, w2sp_h + (long)p * 128 * 64, w2sp_l + (long)p * 128 * 64,
            nullptr, Bsp, NN, nullptr, nullptr, nullptr, nullptr);
        gemm_mfma<128, 64, 0, 0, bf16><<<g_rows, 256, 0, stream>>>(
            h1sh, w2sh_h, w2sh_l, nullptr, Bsh, NN, nullptr, nullptr, nullptr, nullptr);
        spmm_dual<64, 0, 8><<<cdiv(NN, 8), 256, 0, stream>>>(rowptr[p], csr[p], Bsp, Bsh,
                                                             spec_b2 + (long)p * 64, shared_b2,
                                                             spec_stack + (long)p * NN * OUTD,
                                                             shr_stack + (long)p * NN * OUTD);
    }

    // ---- summaries + random walk ----
    {
        dim3 gA(NCH, 3);
        colsum_passA<<<gA, 256, 0, stream>>>(spec_stack, pMax, pSum, pExp);
        colsum_reduceB<<<192, 256, 0, stream>>>(pMax, pSum, pExp, psBuf, zBuf);
        colsum_passC<<<gA, 256, 0, stream>>>(spec_stack, psBuf, zBuf, pEnt);
        colsum_reduceD<<<192, 256, 0, stream>>>(pEnt, psBuf);
    }
    walk_kernel<<<1, 64, 0, stream>>>(psBuf, weight_b, tau, wBuf);

    // ---- H_col (hidden reuses h1sp) ----
    gemm_mfma<192, 128, 1, 2, float><<<g_rows, 256, 0, stream>>>(
        spec_stack, mlp1_h, mlp1_l, mlp_b1, h1sp, NN, nullptr, nullptr, nullptr, nullptr);
    gemm_mfma<128, 64, 0, 0, float><<<g_rows, 256, 0, stream>>>(
        h1sp, mlp2_h, mlp2_l, mlp_b2, Hcol, NN, nullptr, nullptr, nullptr, nullptr);

    // ---- H_raw (U1 reuses h1sh; RB1/RB2 reuse Bsp/Bsh) ----
    float* U1 = h1sh;
    gemm_mfma<256, 64, 0, 0, bf16><<<g_rows, 256, 0, stream>>>(
        feature, raw1_h, raw1_l, nullptr, Bsp, NN, nullptr, nullptr, nullptr, nullptr);
    spmm_merged<<<cdiv(NN, 8), 256, 0, stream>>>(rowptr[0], csr[0],
                                                 rowptr[1], csr[1],
                                                 rowptr[2], csr[2],
                                                 Bsp, wBuf, raw_b1, U1);
    gemm_mfma<64, 64, 0, 0, bf16><<<g_rows, 256, 0, stream>>>(
        U1, raw2_h, raw2_l, nullptr, Bsh, NN, nullptr, nullptr, nullptr, nullptr);
    spmm_merged<<<cdiv(NN, 8), 256, 0, stream>>>(rowptr[0], csr[0],
                                                 rowptr[1], csr[1],
                                                 rowptr[2], csr[2],
                                                 Bsh, wBuf, raw_b2, Hraw);
    hraw_final<<<cdiv((long)NN * OUTD, TB), TB, 0, stream>>>(U1, Hraw);

    // ---- final projection (mix fused into A-loader) ----
    gemm_mfma<256, 64, 2, 0, float><<<g_rows, 256, 0, stream>>>(
        spec_stack, proj_h, proj_l, proj_b, out, NN, wBuf, shr_stack, Hcol, Hraw);
}